// Round 1
// baseline (3140.087 us; speedup 1.0000x reference)
//
#include <hip/hip_runtime.h>
#include <cstdint>

#define N_NODES 118784
#define N_EDGES 1900544
#define NROI 116
#define HID 64
#define D1 3712
#define BATCH 1024

__device__ __forceinline__ float mishf(float x) {
    if (x > 20.f) return x;
    float e = __expf(x);
    float n = e * e + 2.f * e;
    return x * n / (n + 2.f);
}

// --- small weight concat kernels ---------------------------------------------
__global__ void concat1_kernel(const float* __restrict__ w1_l,
                               const float* __restrict__ w1_r,
                               float* __restrict__ Wc1) {
    int i = blockIdx.x * 256 + threadIdx.x;
    if (i < NROI * NROI) {
        Wc1[i] = w1_l[i];
        Wc1[NROI * NROI + i] = w1_r[i];
    }
}

__global__ void concat2_kernel(const float* __restrict__ w2_l,
                               const float* __restrict__ w2_r,
                               float* __restrict__ Wc2) {
    int idx = blockIdx.x * 256 + threadIdx.x;
    if (idx < NROI * 128) {
        int k = idx >> 7, j = idx & 127;
        Wc2[idx] = (j < HID) ? w2_l[k * HID + j] : w2_r[k * HID + (j - HID)];
    }
}

// --- edge scatter (conv1): sum1[dst] += x[src], cnt[dst] += 1 ----------------
__global__ void scatter1_kernel(const int* __restrict__ src,
                                const int* __restrict__ dst,
                                const float* __restrict__ x,
                                float* __restrict__ sum1,
                                float* __restrict__ cnt) {
    long tid = (long)blockIdx.x * 256 + threadIdx.x;
    long e = tid >> 5;
    int f = (int)(tid & 31);
    if (e >= N_EDGES) return;
    int s = src[e], d = dst[e];
    if (f == 0) atomicAdd(&cnt[d], 1.0f);
    const float* xs = x + (long)s * NROI;
    float* sd = sum1 + (long)d * NROI;
#pragma unroll
    for (int i = 0; i < 4; i++) {
        int ff = f + 32 * i;
        if (ff < NROI) atomicAdd(&sd[ff], xs[ff]);
    }
}

// --- turn sums into means in place -------------------------------------------
__global__ void meanize_kernel(float* __restrict__ sum1,
                               const float* __restrict__ cnt) {
    long tid = (long)blockIdx.x * 256 + threadIdx.x;
    long n = tid >> 7;
    int f = (int)(tid & 127);
    if (n >= N_NODES || f >= NROI) return;
    float ic = 1.f / fmaxf(cnt[n], 1.f);
    sum1[n * NROI + f] *= ic;
}

// --- edge scatter (conv2, projected 64-wide): sum2[dst] += q[src][:64] -------
__global__ void scatter2_kernel(const int* __restrict__ src,
                                const int* __restrict__ dst,
                                const float* __restrict__ q,
                                float* __restrict__ sum2) {
    long tid = (long)blockIdx.x * 256 + threadIdx.x;
    long e = tid >> 4;
    int f = (int)(tid & 15);
    if (e >= N_EDGES) return;
    int s = src[e], d = dst[e];
    const float* qs = q + (long)s * 128;
    float* sd = sum2 + (long)d * HID;
#pragma unroll
    for (int i = 0; i < 4; i++) {
        int ff = f + 16 * i;
        atomicAdd(&sd[ff], qs[ff]);
    }
}

// --- conv2 elementwise combine: h2 = mish(sum2/cnt + q_r + b2) ---------------
__global__ void combine2_kernel(const float* __restrict__ sum2,
                                const float* __restrict__ cnt,
                                const float* __restrict__ q,
                                const float* __restrict__ b2,
                                float* __restrict__ h2) {
    long tid = (long)blockIdx.x * 256 + threadIdx.x;
    long n = tid >> 6;
    int f = (int)(tid & 63);
    if (n >= N_NODES) return;
    float c = fmaxf(cnt[n], 1.f);
    float v = sum2[n * HID + f] / c + q[n * 128 + HID + f] + b2[f];
    h2[n * HID + f] = mishf(v);
}

// --- generic tiled fp32 GEMM: C[M,J] = act(A[M,K] @ B[K,J] + bias) -----------
// A is split across two sources: col k < split from A1 (ld1), else A2 (ld2).
__global__ __launch_bounds__(256) void gemm_tiled(
    const float* __restrict__ A1, int ld1, int split,
    const float* __restrict__ A2, int ld2,
    const float* __restrict__ B, const float* __restrict__ bias,
    float* __restrict__ C, int M, int K, int J, int act) {
    __shared__ float As[16][68];   // [k][m], stride 68 -> 16B-aligned rows, no conflicts
    __shared__ float Bs[16][64];   // [k][j]
    const int t = threadIdx.x;
    const int tj = t & 15, tm = t >> 4;
    const long row0 = (long)blockIdx.y * 64;
    const int col0 = blockIdx.x * 64;
    float acc[4][4] = {{0.f}};
    const int ks = t & 15;   // A stage: k
    const int ms = t >> 4;   // A stage: m base
    const int js = t & 63;   // B stage: j
    const int kbs = t >> 6;  // B stage: k base

    for (int k0 = 0; k0 < K; k0 += 16) {
#pragma unroll
        for (int i = 0; i < 4; i++) {
            int m = ms + (i << 4);
            int kk = k0 + ks;
            float v = 0.f;
            if (kk < K) {
                long gm = row0 + m;
                v = (kk < split) ? A1[gm * ld1 + kk] : A2[gm * ld2 + (kk - split)];
            }
            As[ks][m] = v;
        }
#pragma unroll
        for (int i = 0; i < 4; i++) {
            int k = kbs + (i << 2);
            int gk = k0 + k, gj = col0 + js;
            Bs[k][js] = (gk < K && gj < J) ? B[(long)gk * J + gj] : 0.f;
        }
        __syncthreads();
#pragma unroll
        for (int k = 0; k < 16; k++) {
            const float4 a = *(const float4*)&As[k][tm << 2];
            const float4 b = *(const float4*)&Bs[k][tj << 2];
            acc[0][0] += a.x * b.x; acc[0][1] += a.x * b.y; acc[0][2] += a.x * b.z; acc[0][3] += a.x * b.w;
            acc[1][0] += a.y * b.x; acc[1][1] += a.y * b.y; acc[1][2] += a.y * b.z; acc[1][3] += a.y * b.w;
            acc[2][0] += a.z * b.x; acc[2][1] += a.z * b.y; acc[2][2] += a.z * b.z; acc[2][3] += a.z * b.w;
            acc[3][0] += a.w * b.x; acc[3][1] += a.w * b.y; acc[3][2] += a.w * b.z; acc[3][3] += a.w * b.w;
        }
        __syncthreads();
    }
#pragma unroll
    for (int i = 0; i < 4; i++) {
        long grow = row0 + (tm << 2) + i;
#pragma unroll
        for (int j = 0; j < 4; j++) {
            int gcol = col0 + (tj << 2) + j;
            if (gcol < J) {
                float v = acc[i][j] + (bias ? bias[gcol] : 0.f);
                if (act) v = mishf(v);
                C[grow * (long)J + gcol] = v;
            }
        }
    }
}

// --- fused layernorm + mish + lin2 tail --------------------------------------
__global__ __launch_bounds__(256) void tail_kernel(
    const float* __restrict__ t1, const float* __restrict__ g,
    const float* __restrict__ b, const float* __restrict__ w2,
    const float* __restrict__ b2, float* __restrict__ out) {
    int row = blockIdx.x;
    const float* h = t1 + (long)row * D1;
    int t = threadIdx.x;
    int w = t >> 6, lane = t & 63;
    float s = 0.f, ss = 0.f;
    for (int i = t; i < D1; i += 256) {
        float v = h[i];
        s += v;
        ss += v * v;
    }
    for (int d = 32; d > 0; d >>= 1) {
        s += __shfl_down(s, d);
        ss += __shfl_down(ss, d);
    }
    __shared__ float sh[8];
    if (lane == 0) { sh[w] = s; sh[4 + w] = ss; }
    __syncthreads();
    if (t == 0) {
        sh[0] = sh[0] + sh[1] + sh[2] + sh[3];
        sh[4] = sh[4] + sh[5] + sh[6] + sh[7];
    }
    __syncthreads();
    float mu = sh[0] * (1.f / D1);
    float var = sh[4] * (1.f / D1) - mu * mu;
    float rs = rsqrtf(var + 1e-5f);
    float d0 = 0.f, d1 = 0.f;
    for (int i = t; i < D1; i += 256) {
        float v = (h[i] - mu) * rs * g[i] + b[i];
        v = mishf(v);
        d0 += v * w2[2 * i];
        d1 += v * w2[2 * i + 1];
    }
    for (int d = 32; d > 0; d >>= 1) {
        d0 += __shfl_down(d0, d);
        d1 += __shfl_down(d1, d);
    }
    __shared__ float sh2[8];
    if (lane == 0) { sh2[w] = d0; sh2[4 + w] = d1; }
    __syncthreads();
    if (t == 0) {
        out[2 * row] = sh2[0] + sh2[1] + sh2[2] + sh2[3] + b2[0];
        out[2 * row + 1] = sh2[4] + sh2[5] + sh2[6] + sh2[7] + b2[1];
    }
}

extern "C" void kernel_launch(void* const* d_in, const int* in_sizes, int n_in,
                              void* d_out, int out_size, void* d_ws, size_t ws_size,
                              hipStream_t stream) {
    const float* x      = (const float*)d_in[0];
    const int*   ei     = (const int*)d_in[1];
    const float* w1_l   = (const float*)d_in[2];
    const float* b1     = (const float*)d_in[3];
    const float* w1_r   = (const float*)d_in[4];
    const float* w2_l   = (const float*)d_in[5];
    const float* b2     = (const float*)d_in[6];
    const float* w2_r   = (const float*)d_in[7];
    const float* w_lin1 = (const float*)d_in[8];
    const float* b_lin1 = (const float*)d_in[9];
    const float* ln_g   = (const float*)d_in[10];
    const float* ln_b   = (const float*)d_in[11];
    const float* w_lin2 = (const float*)d_in[12];
    const float* b_lin2 = (const float*)d_in[13];
    float* out = (float*)d_out;

    char* ws = (char*)d_ws;
    // workspace layout (bytes):
    //   sum1 (later sum2):  0            .. 55,115,776
    //   cnt:                55,115,776   .. 55,590,912
    //   h1 (later h2 + t1): 55,590,912   .. 110,706,688
    //   q:                  110,706,688  .. 171,524,096
    //   Wc1:                171,524,096  .. 171,631,744
    //   Wc2:                171,631,744  .. 171,691,136
    float* sum1 = (float*)(ws + 0);
    float* cnt  = (float*)(ws + 55115776);
    float* h1   = (float*)(ws + 55590912);
    float* h2   = h1;  // reuse (h1 dead after projection)
    float* t1   = (float*)(ws + 55590912 + 30408704);
    float* q    = (float*)(ws + 110706688);
    float* Wc1  = (float*)(ws + 171524096);
    float* Wc2  = (float*)(ws + 171631744);
    float* sum2 = sum1;  // reuse (sum1 dead after conv1 GEMM)

    const int* src = ei;
    const int* dst = ei + N_EDGES;

    // zero sum1 + cnt (contiguous)
    hipMemsetAsync(sum1, 0, 55590912, stream);

    concat1_kernel<<<(NROI * NROI + 255) / 256, 256, 0, stream>>>(w1_l, w1_r, Wc1);
    concat2_kernel<<<(NROI * 128 + 255) / 256, 256, 0, stream>>>(w2_l, w2_r, Wc2);

    // conv1 aggregation
    scatter1_kernel<<<(int)(((long)N_EDGES * 32 + 255) / 256), 256, 0, stream>>>(
        src, dst, x, sum1, cnt);
    meanize_kernel<<<(int)(((long)N_NODES * 128 + 255) / 256), 256, 0, stream>>>(sum1, cnt);

    // h1 = mish([mean | x] @ [w1_l; w1_r] + b1)
    gemm_tiled<<<dim3(2, N_NODES / 64), 256, 0, stream>>>(
        sum1, NROI, NROI, x, NROI, Wc1, b1, h1, N_NODES, 2 * NROI, NROI, 1);

    // q = h1 @ [w2_l | w2_r]   (projection BEFORE aggregation: linear, so
    // mean(h)@w2_l == mean(h@w2_l); scatters 64-wide instead of 116-wide)
    gemm_tiled<<<dim3(2, N_NODES / 64), 256, 0, stream>>>(
        h1, NROI, NROI, h1, NROI, Wc2, nullptr, q, N_NODES, NROI, 128, 0);

    // conv2 aggregation on projected messages
    hipMemsetAsync(sum2, 0, 30408704, stream);
    scatter2_kernel<<<(int)(((long)N_EDGES * 16 + 255) / 256), 256, 0, stream>>>(
        src, dst, q, sum2);
    combine2_kernel<<<(int)(((long)N_NODES * 64 + 255) / 256), 256, 0, stream>>>(
        sum2, cnt, q, b2, h2);

    // lin1: [1024, 7424] @ [7424, 3712] + b_lin1
    gemm_tiled<<<dim3(D1 / 64, BATCH / 64), 256, 0, stream>>>(
        h2, NROI * HID, NROI * HID, h2, NROI * HID, w_lin1, b_lin1, t1,
        BATCH, NROI * HID, D1, 0);

    // layernorm + mish + lin2
    tail_kernel<<<BATCH, 256, 0, stream>>>(t1, ln_g, ln_b, w_lin2, b_lin2, out);
}

// Round 2
// 2100.586 us; speedup vs baseline: 1.4949x; 1.4949x over previous
//
#include <hip/hip_runtime.h>
#include <hip/hip_bf16.h>
#include <cstdint>

#define N_NODES 118784
#define N_EDGES 1900544
#define NROI 116
#define HID 64
#define D1 3712
#define BATCH 1024
#define KDIM 7424   // N_ROI * HIDDEN

typedef __attribute__((ext_vector_type(8))) short s16x8;
typedef __attribute__((ext_vector_type(4))) float f32x4;

__device__ __forceinline__ float mishf(float x) {
    if (x > 20.f) return x;
    float e = __expf(x);
    float n = e * e + 2.f * e;
    return x * n / (n + 2.f);
}

// --- small weight concat kernels ---------------------------------------------
__global__ void concat1_kernel(const float* __restrict__ w1_l,
                               const float* __restrict__ w1_r,
                               float* __restrict__ Wc1) {
    int i = blockIdx.x * 256 + threadIdx.x;
    if (i < NROI * NROI) {
        Wc1[i] = w1_l[i];
        Wc1[NROI * NROI + i] = w1_r[i];
    }
}

__global__ void concat2_kernel(const float* __restrict__ w2_l,
                               const float* __restrict__ w2_r,
                               float* __restrict__ Wc2) {
    int idx = blockIdx.x * 256 + threadIdx.x;
    if (idx < NROI * 128) {
        int k = idx >> 7, j = idx & 127;
        Wc2[idx] = (j < HID) ? w2_l[k * HID + j] : w2_r[k * HID + (j - HID)];
    }
}

// --- edge scatter (conv1): sum1[dst] += x[src], cnt[dst] += 1 ----------------
__global__ void scatter1_kernel(const int* __restrict__ src,
                                const int* __restrict__ dst,
                                const float* __restrict__ x,
                                float* __restrict__ sum1,
                                float* __restrict__ cnt) {
    long tid = (long)blockIdx.x * 256 + threadIdx.x;
    long e = tid >> 5;
    int f = (int)(tid & 31);
    if (e >= N_EDGES) return;
    int s = src[e], d = dst[e];
    if (f == 0) atomicAdd(&cnt[d], 1.0f);
    const float* xs = x + (long)s * NROI;
    float* sd = sum1 + (long)d * NROI;
#pragma unroll
    for (int i = 0; i < 4; i++) {
        int ff = f + 32 * i;
        if (ff < NROI) atomicAdd(&sd[ff], xs[ff]);
    }
}

// --- turn sums into means in place -------------------------------------------
__global__ void meanize_kernel(float* __restrict__ sum1,
                               const float* __restrict__ cnt) {
    long tid = (long)blockIdx.x * 256 + threadIdx.x;
    long n = tid >> 7;
    int f = (int)(tid & 127);
    if (n >= N_NODES || f >= NROI) return;
    float ic = 1.f / fmaxf(cnt[n], 1.f);
    sum1[n * NROI + f] *= ic;
}

// --- edge scatter (conv2, projected 64-wide): sum2[dst] += q[src][:64] -------
__global__ void scatter2_kernel(const int* __restrict__ src,
                                const int* __restrict__ dst,
                                const float* __restrict__ q,
                                float* __restrict__ sum2) {
    long tid = (long)blockIdx.x * 256 + threadIdx.x;
    long e = tid >> 4;
    int f = (int)(tid & 15);
    if (e >= N_EDGES) return;
    int s = src[e], d = dst[e];
    const float* qs = q + (long)s * 128;
    float* sd = sum2 + (long)d * HID;
#pragma unroll
    for (int i = 0; i < 4; i++) {
        int ff = f + 16 * i;
        atomicAdd(&sd[ff], qs[ff]);
    }
}

// --- conv2 combine: h2bf = bf16(mish(sum2/cnt + q_r + b2)) -------------------
// h2 is consumed only by lin1 (bf16 MFMA), so emit bf16 directly.
__global__ void combine2_kernel(const float* __restrict__ sum2,
                                const float* __restrict__ cnt,
                                const float* __restrict__ q,
                                const float* __restrict__ b2,
                                __hip_bfloat16* __restrict__ h2bf) {
    long tid = (long)blockIdx.x * 256 + threadIdx.x;
    long n = tid >> 6;
    int f = (int)(tid & 63);
    if (n >= N_NODES) return;
    float c = fmaxf(cnt[n], 1.f);
    float v = sum2[n * HID + f] / c + q[n * 128 + HID + f] + b2[f];
    h2bf[n * HID + f] = __float2bfloat16(mishf(v));
}

// --- tiled transpose + fp32->bf16: W[7424][3712] -> WT[3712][7424] -----------
__global__ __launch_bounds__(256) void transpose_bf16_kernel(
    const float* __restrict__ W, __hip_bfloat16* __restrict__ WT) {
    __shared__ float tile[32][33];
    const int t = threadIdx.x;
    const int tn = t & 31, tk = t >> 5;           // tk in 0..7
    const int n0 = blockIdx.x * 32;               // along D1 (3712/32 = 116)
    const int k0 = blockIdx.y * 32;               // along KDIM (7424/32 = 232)
#pragma unroll
    for (int i = 0; i < 4; i++) {
        tile[tk + i * 8][tn] = W[(long)(k0 + tk + i * 8) * D1 + (n0 + tn)];
    }
    __syncthreads();
#pragma unroll
    for (int i = 0; i < 4; i++) {
        int n = n0 + tk + i * 8;
        int k = k0 + tn;
        WT[(long)n * KDIM + k] = __float2bfloat16(tile[tn][tk + i * 8]);
    }
}

// --- lin1 via bf16 MFMA: C[1024][3712] = A[1024][7424] @ B + bias ------------
// A: bf16 row-major (k contiguous). BT: bf16 [3712][7424] (k contiguous).
// 128x128 tile, BK=32, 4 waves each owning a 64x64 quadrant (4x4 MFMA tiles).
__global__ __launch_bounds__(256) void lin1_mfma_kernel(
    const __hip_bfloat16* __restrict__ Abf,
    const __hip_bfloat16* __restrict__ BTbf,
    const float* __restrict__ bias,
    float* __restrict__ C) {
    // stride 40 shorts = 80 B: fragment rows alias 2-way in banks (free),
    // and 80 % 16 == 0 keeps ds_read_b128 alignment.
    __shared__ short As[128][40];
    __shared__ short Bs[128][40];
    const int t = threadIdx.x;
    const long row0 = (long)blockIdx.y * 128;
    const long col0 = (long)blockIdx.x * 128;

    // staging: each thread covers 2 rows x 16B
    const int sr = t >> 2;
    const int sc = (t & 3) << 3;
    const short* Ap = (const short*)Abf + (row0 + sr) * KDIM + sc;
    const short* Bp = (const short*)BTbf + (col0 + sr) * KDIM + sc;

    s16x8 ra0 = *(const s16x8*)(Ap);
    s16x8 ra1 = *(const s16x8*)(Ap + 64 * KDIM);
    s16x8 rb0 = *(const s16x8*)(Bp);
    s16x8 rb1 = *(const s16x8*)(Bp + 64 * KDIM);

    const int lane = t & 63;
    const int wid = t >> 6;
    const int wr = (wid >> 1) << 6;
    const int wc = (wid & 1) << 6;
    const int fm = lane & 15;             // A: row-in-tile, B: col-in-tile
    const int fk = (lane >> 4) << 3;      // k offset 0/8/16/24

    f32x4 acc[4][4];
#pragma unroll
    for (int i = 0; i < 4; i++)
#pragma unroll
        for (int j = 0; j < 4; j++) acc[i][j] = (f32x4){0.f, 0.f, 0.f, 0.f};

    for (int k0 = 0; k0 < KDIM; k0 += 32) {
        *(s16x8*)&As[sr][sc] = ra0;
        *(s16x8*)&As[sr + 64][sc] = ra1;
        *(s16x8*)&Bs[sr][sc] = rb0;
        *(s16x8*)&Bs[sr + 64][sc] = rb1;
        __syncthreads();
        if (k0 + 32 < KDIM) {   // prefetch next tile while computing this one
            ra0 = *(const s16x8*)(Ap + k0 + 32);
            ra1 = *(const s16x8*)(Ap + 64 * KDIM + k0 + 32);
            rb0 = *(const s16x8*)(Bp + k0 + 32);
            rb1 = *(const s16x8*)(Bp + 64 * KDIM + k0 + 32);
        }
        s16x8 a[4], b[4];
#pragma unroll
        for (int i = 0; i < 4; i++) a[i] = *(const s16x8*)&As[wr + i * 16 + fm][fk];
#pragma unroll
        for (int j = 0; j < 4; j++) b[j] = *(const s16x8*)&Bs[wc + j * 16 + fm][fk];
#pragma unroll
        for (int i = 0; i < 4; i++)
#pragma unroll
            for (int j = 0; j < 4; j++)
                acc[i][j] = __builtin_amdgcn_mfma_f32_16x16x32_bf16(
                    a[i], b[j], acc[i][j], 0, 0, 0);
        __syncthreads();
    }

    // epilogue: C/D layout col=lane&15, row=(lane>>4)*4+reg
#pragma unroll
    for (int i = 0; i < 4; i++) {
#pragma unroll
        for (int j = 0; j < 4; j++) {
            int gc = (int)col0 + wc + j * 16 + fm;
            float bv = bias[gc];
#pragma unroll
            for (int r = 0; r < 4; r++) {
                long gr = row0 + wr + i * 16 + ((lane >> 4) << 2) + r;
                C[gr * D1 + gc] = acc[i][j][r] + bv;
            }
        }
    }
}

// --- generic tiled fp32 GEMM (still used for the two small conv GEMMs) -------
__global__ __launch_bounds__(256) void gemm_tiled(
    const float* __restrict__ A1, int ld1, int split,
    const float* __restrict__ A2, int ld2,
    const float* __restrict__ B, const float* __restrict__ bias,
    float* __restrict__ C, int M, int K, int J, int act) {
    __shared__ float As[16][68];
    __shared__ float Bs[16][64];
    const int t = threadIdx.x;
    const int tj = t & 15, tm = t >> 4;
    const long row0 = (long)blockIdx.y * 64;
    const int col0 = blockIdx.x * 64;
    float acc[4][4] = {{0.f}};
    const int ks = t & 15;
    const int ms = t >> 4;
    const int js = t & 63;
    const int kbs = t >> 6;

    for (int k0 = 0; k0 < K; k0 += 16) {
#pragma unroll
        for (int i = 0; i < 4; i++) {
            int m = ms + (i << 4);
            int kk = k0 + ks;
            float v = 0.f;
            if (kk < K) {
                long gm = row0 + m;
                v = (kk < split) ? A1[gm * ld1 + kk] : A2[gm * ld2 + (kk - split)];
            }
            As[ks][m] = v;
        }
#pragma unroll
        for (int i = 0; i < 4; i++) {
            int k = kbs + (i << 2);
            int gk = k0 + k, gj = col0 + js;
            Bs[k][js] = (gk < K && gj < J) ? B[(long)gk * J + gj] : 0.f;
        }
        __syncthreads();
#pragma unroll
        for (int k = 0; k < 16; k++) {
            const float4 a = *(const float4*)&As[k][tm << 2];
            const float4 b = *(const float4*)&Bs[k][tj << 2];
            acc[0][0] += a.x * b.x; acc[0][1] += a.x * b.y; acc[0][2] += a.x * b.z; acc[0][3] += a.x * b.w;
            acc[1][0] += a.y * b.x; acc[1][1] += a.y * b.y; acc[1][2] += a.y * b.z; acc[1][3] += a.y * b.w;
            acc[2][0] += a.z * b.x; acc[2][1] += a.z * b.y; acc[2][2] += a.z * b.z; acc[2][3] += a.z * b.w;
            acc[3][0] += a.w * b.x; acc[3][1] += a.w * b.y; acc[3][2] += a.w * b.z; acc[3][3] += a.w * b.w;
        }
        __syncthreads();
    }
#pragma unroll
    for (int i = 0; i < 4; i++) {
        long grow = row0 + (tm << 2) + i;
#pragma unroll
        for (int j = 0; j < 4; j++) {
            int gcol = col0 + (tj << 2) + j;
            if (gcol < J) {
                float v = acc[i][j] + (bias ? bias[gcol] : 0.f);
                if (act) v = mishf(v);
                C[grow * (long)J + gcol] = v;
            }
        }
    }
}

// --- fused layernorm + mish + lin2 tail --------------------------------------
__global__ __launch_bounds__(256) void tail_kernel(
    const float* __restrict__ t1, const float* __restrict__ g,
    const float* __restrict__ b, const float* __restrict__ w2,
    const float* __restrict__ b2, float* __restrict__ out) {
    int row = blockIdx.x;
    const float* h = t1 + (long)row * D1;
    int t = threadIdx.x;
    int w = t >> 6, lane = t & 63;
    float s = 0.f, ss = 0.f;
    for (int i = t; i < D1; i += 256) {
        float v = h[i];
        s += v;
        ss += v * v;
    }
    for (int d = 32; d > 0; d >>= 1) {
        s += __shfl_down(s, d);
        ss += __shfl_down(ss, d);
    }
    __shared__ float sh[8];
    if (lane == 0) { sh[w] = s; sh[4 + w] = ss; }
    __syncthreads();
    if (t == 0) {
        sh[0] = sh[0] + sh[1] + sh[2] + sh[3];
        sh[4] = sh[4] + sh[5] + sh[6] + sh[7];
    }
    __syncthreads();
    float mu = sh[0] * (1.f / D1);
    float var = sh[4] * (1.f / D1) - mu * mu;
    float rs = rsqrtf(var + 1e-5f);
    float d0 = 0.f, d1 = 0.f;
    for (int i = t; i < D1; i += 256) {
        float v = (h[i] - mu) * rs * g[i] + b[i];
        v = mishf(v);
        d0 += v * w2[2 * i];
        d1 += v * w2[2 * i + 1];
    }
    for (int d = 32; d > 0; d >>= 1) {
        d0 += __shfl_down(d0, d);
        d1 += __shfl_down(d1, d);
    }
    __shared__ float sh2[8];
    if (lane == 0) { sh2[w] = d0; sh2[4 + w] = d1; }
    __syncthreads();
    if (t == 0) {
        out[2 * row] = sh2[0] + sh2[1] + sh2[2] + sh2[3] + b2[0];
        out[2 * row + 1] = sh2[4] + sh2[5] + sh2[6] + sh2[7] + b2[1];
    }
}

extern "C" void kernel_launch(void* const* d_in, const int* in_sizes, int n_in,
                              void* d_out, int out_size, void* d_ws, size_t ws_size,
                              hipStream_t stream) {
    const float* x      = (const float*)d_in[0];
    const int*   ei     = (const int*)d_in[1];
    const float* w1_l   = (const float*)d_in[2];
    const float* b1     = (const float*)d_in[3];
    const float* w1_r   = (const float*)d_in[4];
    const float* w2_l   = (const float*)d_in[5];
    const float* b2     = (const float*)d_in[6];
    const float* w2_r   = (const float*)d_in[7];
    const float* w_lin1 = (const float*)d_in[8];
    const float* b_lin1 = (const float*)d_in[9];
    const float* ln_g   = (const float*)d_in[10];
    const float* ln_b   = (const float*)d_in[11];
    const float* w_lin2 = (const float*)d_in[12];
    const float* b_lin2 = (const float*)d_in[13];
    float* out = (float*)d_out;

    char* ws = (char*)d_ws;
    // workspace layout (bytes), with liveness-based reuse:
    //   [0,          55,115,776)  sum1 -> sum2 (sum1 dead after conv1 GEMM)
    //   [55,115,776, 55,590,912)  cnt
    //   [55,590,912, 86,   ...)   h1 (fp32, 30.4MB) -> h2bf (bf16, 15.2MB)
    //   [85,999,616, 101,..   )   t1 (15.2MB)
    //   [110,706,688,171,524,096) q (60.8MB) -> wT (55.1MB, after combine2)
    //   [171,524,096,...)         Wc1, Wc2
    float* sum1 = (float*)(ws + 0);
    float* cnt  = (float*)(ws + 55115776);
    float* h1   = (float*)(ws + 55590912);
    __hip_bfloat16* h2bf = (__hip_bfloat16*)(ws + 55590912);  // reuse (h1 dead after projection)
    float* t1   = (float*)(ws + 55590912 + 30408704);
    float* q    = (float*)(ws + 110706688);
    __hip_bfloat16* wT = (__hip_bfloat16*)(ws + 110706688);   // reuse (q dead after combine2)
    float* Wc1  = (float*)(ws + 171524096);
    float* Wc2  = (float*)(ws + 171631744);
    float* sum2 = sum1;

    const int* src = ei;
    const int* dst = ei + N_EDGES;

    // zero sum1 + cnt (contiguous)
    hipMemsetAsync(sum1, 0, 55590912, stream);

    concat1_kernel<<<(NROI * NROI + 255) / 256, 256, 0, stream>>>(w1_l, w1_r, Wc1);
    concat2_kernel<<<(NROI * 128 + 255) / 256, 256, 0, stream>>>(w2_l, w2_r, Wc2);

    // conv1 aggregation
    scatter1_kernel<<<(int)(((long)N_EDGES * 32 + 255) / 256), 256, 0, stream>>>(
        src, dst, x, sum1, cnt);
    meanize_kernel<<<(int)(((long)N_NODES * 128 + 255) / 256), 256, 0, stream>>>(sum1, cnt);

    // h1 = mish([mean | x] @ [w1_l; w1_r] + b1)
    gemm_tiled<<<dim3(2, N_NODES / 64), 256, 0, stream>>>(
        sum1, NROI, NROI, x, NROI, Wc1, b1, h1, N_NODES, 2 * NROI, NROI, 1);

    // q = h1 @ [w2_l | w2_r]  (project BEFORE aggregate: mean(h)@w == mean(h@w))
    gemm_tiled<<<dim3(2, N_NODES / 64), 256, 0, stream>>>(
        h1, NROI, NROI, h1, NROI, Wc2, nullptr, q, N_NODES, NROI, 128, 0);

    // conv2 aggregation on projected messages
    hipMemsetAsync(sum2, 0, 30408704, stream);
    scatter2_kernel<<<(int)(((long)N_EDGES * 16 + 255) / 256), 256, 0, stream>>>(
        src, dst, q, sum2);
    combine2_kernel<<<(int)(((long)N_NODES * 64 + 255) / 256), 256, 0, stream>>>(
        sum2, cnt, q, b2, h2bf);

    // w_lin1 -> wT (bf16, transposed) ; must come AFTER combine2 (q overlap)
    transpose_bf16_kernel<<<dim3(D1 / 32, KDIM / 32), 256, 0, stream>>>(w_lin1, wT);

    // lin1 via bf16 MFMA: t1[1024][3712] = h2bf @ w_lin1 + b_lin1
    lin1_mfma_kernel<<<dim3(D1 / 128, BATCH / 128), 256, 0, stream>>>(
        h2bf, wT, b_lin1, t1);

    // layernorm + mish + lin2
    tail_kernel<<<BATCH, 256, 0, stream>>>(t1, ln_g, ln_b, w_lin2, b_lin2, out);
}

// Round 3
// 1035.962 us; speedup vs baseline: 3.0311x; 2.0277x over previous
//
#include <hip/hip_runtime.h>
#include <hip/hip_bf16.h>
#include <cstdint>

#define N_NODES 118784
#define N_EDGES 1900544
#define NROI 116
#define HID 64
#define D1 3712
#define BATCH 1024
#define KDIM 7424   // N_ROI * HIDDEN

typedef __attribute__((ext_vector_type(8))) short s16x8;
typedef __attribute__((ext_vector_type(4))) float f32x4;

__device__ __forceinline__ float mishf(float x) {
    if (x > 20.f) return x;
    float e = __expf(x);
    float n = e * e + 2.f * e;
    return x * n / (n + 2.f);
}

// --- small weight concat kernels ---------------------------------------------
__global__ void concat1_kernel(const float* __restrict__ w1_l,
                               const float* __restrict__ w1_r,
                               float* __restrict__ Wc1) {
    int i = blockIdx.x * 256 + threadIdx.x;
    if (i < NROI * NROI) {
        Wc1[i] = w1_l[i];
        Wc1[NROI * NROI + i] = w1_r[i];
    }
}

__global__ void concat2_kernel(const float* __restrict__ w2_l,
                               const float* __restrict__ w2_r,
                               float* __restrict__ Wc2) {
    int idx = blockIdx.x * 256 + threadIdx.x;
    if (idx < NROI * 128) {
        int k = idx >> 7, j = idx & 127;
        Wc2[idx] = (j < HID) ? w2_l[k * HID + j] : w2_r[k * HID + (j - HID)];
    }
}

// --- CSR build: histogram -> exclusive scan -> cursor fill -------------------
__global__ void hist_kernel(const int* __restrict__ dst, int* __restrict__ cnt) {
    int e = blockIdx.x * 256 + threadIdx.x;
    if (e < N_EDGES) atomicAdd(&cnt[dst[e]], 1);
}

// per-block exclusive scan of cnt -> cursor, block totals -> bsum
__global__ __launch_bounds__(256) void scan1_kernel(const int* __restrict__ cnt,
                                                    int* __restrict__ cursor,
                                                    int* __restrict__ bsum) {
    __shared__ int sh[256];
    int t = threadIdx.x;
    int i = blockIdx.x * 256 + t;
    int v = cnt[i];
    sh[t] = v;
    __syncthreads();
    for (int d = 1; d < 256; d <<= 1) {
        int a = (t >= d) ? sh[t - d] : 0;
        __syncthreads();
        sh[t] += a;
        __syncthreads();
    }
    cursor[i] = sh[t] - v;   // exclusive within block
    if (t == 255) bsum[blockIdx.x] = sh[255];
}

// single-block exclusive scan of the 464 block sums (in place)
__global__ __launch_bounds__(512) void scan2_kernel(int* __restrict__ bsum, int nb) {
    __shared__ int sh[512];
    int t = threadIdx.x;
    int v = (t < nb) ? bsum[t] : 0;
    sh[t] = v;
    __syncthreads();
    for (int d = 1; d < 512; d <<= 1) {
        int a = (t >= d) ? sh[t - d] : 0;
        __syncthreads();
        sh[t] += a;
        __syncthreads();
    }
    if (t < nb) bsum[t] = sh[t] - v;
}

__global__ void scan3_kernel(int* __restrict__ cursor, const int* __restrict__ bsum) {
    int i = blockIdx.x * 256 + threadIdx.x;
    cursor[i] += bsum[blockIdx.x];
}

// fill: ssrc sorted-by-dst; cursor[n] ends at rowptr_end (start = end - cnt)
__global__ void fill_kernel(const int* __restrict__ src, const int* __restrict__ dst,
                            int* __restrict__ cursor, int* __restrict__ ssrc) {
    int e = blockIdx.x * 256 + threadIdx.x;
    if (e >= N_EDGES) return;
    int d = dst[e];
    int pos = atomicAdd(&cursor[d], 1);
    ssrc[pos] = src[e];
}

// --- conv1 aggregation by gather: mean1[n] = mean_{j in N(n)} x[j] -----------
// one wave per node; lanes 0..57 each own a float2 of the 116-wide row
__global__ __launch_bounds__(256) void gather1_kernel(
    const int* __restrict__ ssrc, const int* __restrict__ cursor,
    const int* __restrict__ cnt, const float* __restrict__ x,
    float* __restrict__ mean1) {
    int node = blockIdx.x * 4 + (threadIdx.x >> 6);
    int lane = threadIdx.x & 63;
    if (node >= N_NODES) return;
    int deg = cnt[node];
    int start = cursor[node] - deg;   // cursor holds end after fill
    float sx = 0.f, sy = 0.f;
    for (int base = 0; base < deg; base += 64) {
        int n = min(deg - base, 64);
        int idx = (lane < n) ? ssrc[start + base + lane] : 0;
        int j = 0;
        for (; j + 1 < n; j += 2) {
            int s0 = __shfl(idx, j), s1 = __shfl(idx, j + 1);
            if (lane < 58) {
                float2 v0 = *(const float2*)(x + (long)s0 * NROI + 2 * lane);
                float2 v1 = *(const float2*)(x + (long)s1 * NROI + 2 * lane);
                sx += v0.x + v1.x;
                sy += v0.y + v1.y;
            }
        }
        if (j < n) {
            int s0 = __shfl(idx, j);
            if (lane < 58) {
                float2 v0 = *(const float2*)(x + (long)s0 * NROI + 2 * lane);
                sx += v0.x;
                sy += v0.y;
            }
        }
    }
    float inv = 1.f / fmaxf((float)deg, 1.f);
    if (lane < 58) {
        float2 o = {sx * inv, sy * inv};
        *(float2*)(mean1 + (long)node * NROI + 2 * lane) = o;
    }
}

// --- conv2 aggregation by gather on projected bf16 messages ------------------
// h2bf[n] = bf16(mish(mean_j ql[j] + qr[n] + b2)); q row = [ql(64) | qr(64)]
__global__ __launch_bounds__(256) void gather2_kernel(
    const int* __restrict__ ssrc, const int* __restrict__ cursor,
    const int* __restrict__ cnt, const __hip_bfloat16* __restrict__ q,
    const float* __restrict__ b2, __hip_bfloat16* __restrict__ h2bf) {
    int node = blockIdx.x * 4 + (threadIdx.x >> 6);
    int lane = threadIdx.x & 63;
    if (node >= N_NODES) return;
    int deg = cnt[node];
    int start = cursor[node] - deg;
    float s = 0.f;
    for (int base = 0; base < deg; base += 64) {
        int n = min(deg - base, 64);
        int idx = (lane < n) ? ssrc[start + base + lane] : 0;
        int j = 0;
        for (; j + 1 < n; j += 2) {
            int s0 = __shfl(idx, j), s1 = __shfl(idx, j + 1);
            float v0 = __bfloat162float(q[(long)s0 * 128 + lane]);
            float v1 = __bfloat162float(q[(long)s1 * 128 + lane]);
            s += v0 + v1;
        }
        if (j < n) {
            int s0 = __shfl(idx, j);
            s += __bfloat162float(q[(long)s0 * 128 + lane]);
        }
    }
    float c = fmaxf((float)deg, 1.f);
    float qr = __bfloat162float(q[(long)node * 128 + 64 + lane]);
    float v = s / c + qr + b2[lane];
    h2bf[(long)node * HID + lane] = __float2bfloat16(mishf(v));
}

// --- tiled transpose + fp32->bf16: W[7424][3712] -> WT[3712][7424] -----------
__global__ __launch_bounds__(256) void transpose_bf16_kernel(
    const float* __restrict__ W, __hip_bfloat16* __restrict__ WT) {
    __shared__ float tile[32][33];
    const int t = threadIdx.x;
    const int tn = t & 31, tk = t >> 5;
    const int n0 = blockIdx.x * 32;
    const int k0 = blockIdx.y * 32;
#pragma unroll
    for (int i = 0; i < 4; i++) {
        tile[tk + i * 8][tn] = W[(long)(k0 + tk + i * 8) * D1 + (n0 + tn)];
    }
    __syncthreads();
#pragma unroll
    for (int i = 0; i < 4; i++) {
        int n = n0 + tk + i * 8;
        int k = k0 + tn;
        WT[(long)n * KDIM + k] = __float2bfloat16(tile[tn][tk + i * 8]);
    }
}

// --- lin1 via bf16 MFMA: C[1024][3712] = A[1024][7424] @ B + bias ------------
__global__ __launch_bounds__(256) void lin1_mfma_kernel(
    const __hip_bfloat16* __restrict__ Abf,
    const __hip_bfloat16* __restrict__ BTbf,
    const float* __restrict__ bias,
    float* __restrict__ C) {
    __shared__ short As[128][40];
    __shared__ short Bs[128][40];
    const int t = threadIdx.x;
    const long row0 = (long)blockIdx.y * 128;
    const long col0 = (long)blockIdx.x * 128;

    const int sr = t >> 2;
    const int sc = (t & 3) << 3;
    const short* Ap = (const short*)Abf + (row0 + sr) * KDIM + sc;
    const short* Bp = (const short*)BTbf + (col0 + sr) * KDIM + sc;

    s16x8 ra0 = *(const s16x8*)(Ap);
    s16x8 ra1 = *(const s16x8*)(Ap + 64 * KDIM);
    s16x8 rb0 = *(const s16x8*)(Bp);
    s16x8 rb1 = *(const s16x8*)(Bp + 64 * KDIM);

    const int lane = t & 63;
    const int wid = t >> 6;
    const int wr = (wid >> 1) << 6;
    const int wc = (wid & 1) << 6;
    const int fm = lane & 15;
    const int fk = (lane >> 4) << 3;

    f32x4 acc[4][4];
#pragma unroll
    for (int i = 0; i < 4; i++)
#pragma unroll
        for (int j = 0; j < 4; j++) acc[i][j] = (f32x4){0.f, 0.f, 0.f, 0.f};

    for (int k0 = 0; k0 < KDIM; k0 += 32) {
        *(s16x8*)&As[sr][sc] = ra0;
        *(s16x8*)&As[sr + 64][sc] = ra1;
        *(s16x8*)&Bs[sr][sc] = rb0;
        *(s16x8*)&Bs[sr + 64][sc] = rb1;
        __syncthreads();
        if (k0 + 32 < KDIM) {
            ra0 = *(const s16x8*)(Ap + k0 + 32);
            ra1 = *(const s16x8*)(Ap + 64 * KDIM + k0 + 32);
            rb0 = *(const s16x8*)(Bp + k0 + 32);
            rb1 = *(const s16x8*)(Bp + 64 * KDIM + k0 + 32);
        }
        s16x8 a[4], b[4];
#pragma unroll
        for (int i = 0; i < 4; i++) a[i] = *(const s16x8*)&As[wr + i * 16 + fm][fk];
#pragma unroll
        for (int j = 0; j < 4; j++) b[j] = *(const s16x8*)&Bs[wc + j * 16 + fm][fk];
#pragma unroll
        for (int i = 0; i < 4; i++)
#pragma unroll
            for (int j = 0; j < 4; j++)
                acc[i][j] = __builtin_amdgcn_mfma_f32_16x16x32_bf16(
                    a[i], b[j], acc[i][j], 0, 0, 0);
        __syncthreads();
    }

#pragma unroll
    for (int i = 0; i < 4; i++) {
#pragma unroll
        for (int j = 0; j < 4; j++) {
            int gc = (int)col0 + wc + j * 16 + fm;
            float bv = bias[gc];
#pragma unroll
            for (int r = 0; r < 4; r++) {
                long gr = row0 + wr + i * 16 + ((lane >> 4) << 2) + r;
                C[gr * D1 + gc] = acc[i][j][r] + bv;
            }
        }
    }
}

// --- generic tiled fp32 GEMM (conv GEMMs); optional bf16 output --------------
__global__ __launch_bounds__(256) void gemm_tiled(
    const float* __restrict__ A1, int ld1, int split,
    const float* __restrict__ A2, int ld2,
    const float* __restrict__ B, const float* __restrict__ bias,
    float* __restrict__ C, __hip_bfloat16* __restrict__ Cb,
    int M, int K, int J, int act) {
    __shared__ float As[16][68];
    __shared__ float Bs[16][64];
    const int t = threadIdx.x;
    const int tj = t & 15, tm = t >> 4;
    const long row0 = (long)blockIdx.y * 64;
    const int col0 = blockIdx.x * 64;
    float acc[4][4] = {{0.f}};
    const int ks = t & 15;
    const int ms = t >> 4;
    const int js = t & 63;
    const int kbs = t >> 6;

    for (int k0 = 0; k0 < K; k0 += 16) {
#pragma unroll
        for (int i = 0; i < 4; i++) {
            int m = ms + (i << 4);
            int kk = k0 + ks;
            float v = 0.f;
            if (kk < K) {
                long gm = row0 + m;
                v = (kk < split) ? A1[gm * ld1 + kk] : A2[gm * ld2 + (kk - split)];
            }
            As[ks][m] = v;
        }
#pragma unroll
        for (int i = 0; i < 4; i++) {
            int k = kbs + (i << 2);
            int gk = k0 + k, gj = col0 + js;
            Bs[k][js] = (gk < K && gj < J) ? B[(long)gk * J + gj] : 0.f;
        }
        __syncthreads();
#pragma unroll
        for (int k = 0; k < 16; k++) {
            const float4 a = *(const float4*)&As[k][tm << 2];
            const float4 b = *(const float4*)&Bs[k][tj << 2];
            acc[0][0] += a.x * b.x; acc[0][1] += a.x * b.y; acc[0][2] += a.x * b.z; acc[0][3] += a.x * b.w;
            acc[1][0] += a.y * b.x; acc[1][1] += a.y * b.y; acc[1][2] += a.y * b.z; acc[1][3] += a.y * b.w;
            acc[2][0] += a.z * b.x; acc[2][1] += a.z * b.y; acc[2][2] += a.z * b.z; acc[2][3] += a.z * b.w;
            acc[3][0] += a.w * b.x; acc[3][1] += a.w * b.y; acc[3][2] += a.w * b.z; acc[3][3] += a.w * b.w;
        }
        __syncthreads();
    }
#pragma unroll
    for (int i = 0; i < 4; i++) {
        long grow = row0 + (tm << 2) + i;
#pragma unroll
        for (int j = 0; j < 4; j++) {
            int gcol = col0 + (tj << 2) + j;
            if (gcol < J) {
                float v = acc[i][j] + (bias ? bias[gcol] : 0.f);
                if (act) v = mishf(v);
                if (Cb) Cb[grow * (long)J + gcol] = __float2bfloat16(v);
                else    C[grow * (long)J + gcol] = v;
            }
        }
    }
}

// --- fused layernorm + mish + lin2 tail --------------------------------------
__global__ __launch_bounds__(256) void tail_kernel(
    const float* __restrict__ t1, const float* __restrict__ g,
    const float* __restrict__ b, const float* __restrict__ w2,
    const float* __restrict__ b2, float* __restrict__ out) {
    int row = blockIdx.x;
    const float* h = t1 + (long)row * D1;
    int t = threadIdx.x;
    int w = t >> 6, lane = t & 63;
    float s = 0.f, ss = 0.f;
    for (int i = t; i < D1; i += 256) {
        float v = h[i];
        s += v;
        ss += v * v;
    }
    for (int d = 32; d > 0; d >>= 1) {
        s += __shfl_down(s, d);
        ss += __shfl_down(ss, d);
    }
    __shared__ float sh[8];
    if (lane == 0) { sh[w] = s; sh[4 + w] = ss; }
    __syncthreads();
    if (t == 0) {
        sh[0] = sh[0] + sh[1] + sh[2] + sh[3];
        sh[4] = sh[4] + sh[5] + sh[6] + sh[7];
    }
    __syncthreads();
    float mu = sh[0] * (1.f / D1);
    float var = sh[4] * (1.f / D1) - mu * mu;
    float rs = rsqrtf(var + 1e-5f);
    float d0 = 0.f, d1 = 0.f;
    for (int i = t; i < D1; i += 256) {
        float v = (h[i] - mu) * rs * g[i] + b[i];
        v = mishf(v);
        d0 += v * w2[2 * i];
        d1 += v * w2[2 * i + 1];
    }
    for (int d = 32; d > 0; d >>= 1) {
        d0 += __shfl_down(d0, d);
        d1 += __shfl_down(d1, d);
    }
    __shared__ float sh2[8];
    if (lane == 0) { sh2[w] = d0; sh2[4 + w] = d1; }
    __syncthreads();
    if (t == 0) {
        out[2 * row] = sh2[0] + sh2[1] + sh2[2] + sh2[3] + b2[0];
        out[2 * row + 1] = sh2[4] + sh2[5] + sh2[6] + sh2[7] + b2[1];
    }
}

extern "C" void kernel_launch(void* const* d_in, const int* in_sizes, int n_in,
                              void* d_out, int out_size, void* d_ws, size_t ws_size,
                              hipStream_t stream) {
    const float* x      = (const float*)d_in[0];
    const int*   ei     = (const int*)d_in[1];
    const float* w1_l   = (const float*)d_in[2];
    const float* b1     = (const float*)d_in[3];
    const float* w1_r   = (const float*)d_in[4];
    const float* w2_l   = (const float*)d_in[5];
    const float* b2     = (const float*)d_in[6];
    const float* w2_r   = (const float*)d_in[7];
    const float* w_lin1 = (const float*)d_in[8];
    const float* b_lin1 = (const float*)d_in[9];
    const float* ln_g   = (const float*)d_in[10];
    const float* ln_b   = (const float*)d_in[11];
    const float* w_lin2 = (const float*)d_in[12];
    const float* b_lin2 = (const float*)d_in[13];
    float* out = (float*)d_out;

    char* ws = (char*)d_ws;
    // workspace layout (bytes), liveness-based reuse (fits in proven >=171.7MB):
    //   A [0,          55,115,776)  mean1 (gather1->conv1) -> wT bf16 (transpose->lin1)
    //   B [55,115,776, 55,590,912)  cnt (int)
    //   C [55,590,912, 110,706,688) h1 fp32 55.1MB (conv1->gemm2)
    //       -> h2bf bf16 15.2MB at C+0 (gather2->lin1)
    //       -> t1 fp32 15.2MB at C+30,408,704 (lin1->tail)
    //   D [110,706,688,141,115,392) q bf16 [N,128] (gemm2->gather2)
    //     [141,115,392,141,590,528) cursor (int)
    //     [141,590,528,141,592,576) bsum (int, 512)
    //     [141,592,576,149,194,752) ssrc (int, E)
    //   E [171,524,096,171,631,744) Wc1
    //   F [171,631,744,171,691,136) Wc2
    float* mean1 = (float*)(ws + 0);
    __hip_bfloat16* wT = (__hip_bfloat16*)(ws + 0);
    int*   cnt    = (int*)(ws + 55115776);
    float* h1     = (float*)(ws + 55590912);
    __hip_bfloat16* h2bf = (__hip_bfloat16*)(ws + 55590912);
    float* t1     = (float*)(ws + 55590912 + 30408704);
    __hip_bfloat16* q = (__hip_bfloat16*)(ws + 110706688);
    int*   cursor = (int*)(ws + 141115392);
    int*   bsum   = (int*)(ws + 141590528);
    int*   ssrc   = (int*)(ws + 141592576);
    float* Wc1    = (float*)(ws + 171524096);
    float* Wc2    = (float*)(ws + 171631744);

    const int* src = ei;
    const int* dst = ei + N_EDGES;

    const int NB = N_NODES / 256;          // 464 scan blocks
    const int EB = (N_EDGES + 255) / 256;  // edge-grid blocks

    // --- CSR build ---
    hipMemsetAsync(cnt, 0, N_NODES * sizeof(int), stream);
    hist_kernel<<<EB, 256, 0, stream>>>(dst, cnt);
    scan1_kernel<<<NB, 256, 0, stream>>>(cnt, cursor, bsum);
    scan2_kernel<<<1, 512, 0, stream>>>(bsum, NB);
    scan3_kernel<<<NB, 256, 0, stream>>>(cursor, bsum);
    fill_kernel<<<EB, 256, 0, stream>>>(src, dst, cursor, ssrc);

    concat1_kernel<<<(NROI * NROI + 255) / 256, 256, 0, stream>>>(w1_l, w1_r, Wc1);
    concat2_kernel<<<(NROI * 128 + 255) / 256, 256, 0, stream>>>(w2_l, w2_r, Wc2);

    // --- conv1: gather-mean then fused GEMM ---
    gather1_kernel<<<(N_NODES + 3) / 4, 256, 0, stream>>>(ssrc, cursor, cnt, x, mean1);
    gemm_tiled<<<dim3(2, N_NODES / 64), 256, 0, stream>>>(
        mean1, NROI, NROI, x, NROI, Wc1, b1, h1, nullptr, N_NODES, 2 * NROI, NROI, 1);

    // --- conv2: project first (q = h1 @ [w2_l|w2_r], bf16), gather, combine ---
    gemm_tiled<<<dim3(2, N_NODES / 64), 256, 0, stream>>>(
        h1, NROI, NROI, h1, NROI, Wc2, nullptr, nullptr, q, N_NODES, NROI, 128, 0);
    gather2_kernel<<<(N_NODES + 3) / 4, 256, 0, stream>>>(ssrc, cursor, cnt, q, b2, h2bf);

    // --- lin1 (bf16 MFMA) ---
    transpose_bf16_kernel<<<dim3(D1 / 32, KDIM / 32), 256, 0, stream>>>(w_lin1, wT);
    lin1_mfma_kernel<<<dim3(D1 / 128, BATCH / 128), 256, 0, stream>>>(h2bf, wT, b_lin1, t1);

    // --- layernorm + mish + lin2 ---
    tail_kernel<<<BATCH, 256, 0, stream>>>(t1, ln_g, ln_b, w_lin2, b_lin2, out);
}

// Round 4
// 899.200 us; speedup vs baseline: 3.4921x; 1.1521x over previous
//
#include <hip/hip_runtime.h>
#include <hip/hip_bf16.h>
#include <cstdint>

#define N_NODES 118784
#define N_EDGES 1900544
#define NROI 116
#define HID 64
#define D1 3712
#define BATCH 1024
#define KDIM 7424   // N_ROI * HIDDEN

typedef __attribute__((ext_vector_type(8))) short s16x8;
typedef __attribute__((ext_vector_type(4))) float f32x4;

__device__ __forceinline__ float mishf(float x) {
    if (x > 20.f) return x;
    float e = __expf(x);
    float n = e * e + 2.f * e;
    return x * n / (n + 2.f);
}

// --- build BT1 [128][256] bf16 (padded [w1_l; w1_r]^T) + bias1p[128] ---------
__global__ void concat1_kernel(const float* __restrict__ w1_l,
                               const float* __restrict__ w1_r,
                               const float* __restrict__ b1,
                               __hip_bfloat16* __restrict__ BT1,
                               float* __restrict__ bias1p) {
    int idx = blockIdx.x * 256 + threadIdx.x;
    if (idx >= 128 * 256) return;
    int j = idx >> 8, k = idx & 255;
    float v = 0.f;
    if (j < NROI) {
        if (k < NROI) v = w1_l[k * NROI + j];
        else if (k < 2 * NROI) v = w1_r[(k - NROI) * NROI + j];
    }
    BT1[idx] = __float2bfloat16(v);
    if (idx < 128) bias1p[idx] = (idx < NROI) ? b1[idx] : 0.f;
}

// --- build BT2 [128][128] bf16 (padded [w2_l | w2_r]^T) ----------------------
__global__ void concat2_kernel(const float* __restrict__ w2_l,
                               const float* __restrict__ w2_r,
                               __hip_bfloat16* __restrict__ BT2) {
    int idx = blockIdx.x * 256 + threadIdx.x;
    if (idx >= 128 * 128) return;
    int j = idx >> 7, k = idx & 127;
    float v = 0.f;
    if (k < NROI) v = (j < HID) ? w2_l[k * HID + j] : w2_r[k * HID + (j - HID)];
    BT2[idx] = __float2bfloat16(v);
}

// --- CSR build: histogram -> exclusive scan -> cursor fill -------------------
__global__ void hist_kernel(const int* __restrict__ dst, int* __restrict__ cnt) {
    int e = blockIdx.x * 256 + threadIdx.x;
    if (e < N_EDGES) atomicAdd(&cnt[dst[e]], 1);
}

__global__ __launch_bounds__(256) void scan1_kernel(const int* __restrict__ cnt,
                                                    int* __restrict__ cursor,
                                                    int* __restrict__ bsum) {
    __shared__ int sh[256];
    int t = threadIdx.x;
    int i = blockIdx.x * 256 + t;
    int v = cnt[i];
    sh[t] = v;
    __syncthreads();
    for (int d = 1; d < 256; d <<= 1) {
        int a = (t >= d) ? sh[t - d] : 0;
        __syncthreads();
        sh[t] += a;
        __syncthreads();
    }
    cursor[i] = sh[t] - v;
    if (t == 255) bsum[blockIdx.x] = sh[255];
}

__global__ __launch_bounds__(512) void scan2_kernel(int* __restrict__ bsum, int nb) {
    __shared__ int sh[512];
    int t = threadIdx.x;
    int v = (t < nb) ? bsum[t] : 0;
    sh[t] = v;
    __syncthreads();
    for (int d = 1; d < 512; d <<= 1) {
        int a = (t >= d) ? sh[t - d] : 0;
        __syncthreads();
        sh[t] += a;
        __syncthreads();
    }
    if (t < nb) bsum[t] = sh[t] - v;
}

__global__ void scan3_kernel(int* __restrict__ cursor, const int* __restrict__ bsum) {
    int i = blockIdx.x * 256 + threadIdx.x;
    cursor[i] += bsum[blockIdx.x];
}

__global__ void fill_kernel(const int* __restrict__ src, const int* __restrict__ dst,
                            int* __restrict__ cursor, int* __restrict__ ssrc) {
    int e = blockIdx.x * 256 + threadIdx.x;
    if (e >= N_EDGES) return;
    int d = dst[e];
    int pos = atomicAdd(&cursor[d], 1);
    ssrc[pos] = src[e];
}

// --- conv1 aggregation by gather, emitting packed bf16 A-matrix --------------
// Ac1[n] = [ bf16(mean_{j in N(n)} x[j]) (116) | bf16(x[n]) (116) | 0 (24) ]
__global__ __launch_bounds__(256) void gather1_kernel(
    const int* __restrict__ ssrc, const int* __restrict__ cursor,
    const int* __restrict__ cnt, const float* __restrict__ x,
    __hip_bfloat16* __restrict__ Ac1) {
    int node = blockIdx.x * 4 + (threadIdx.x >> 6);
    int lane = threadIdx.x & 63;
    if (node >= N_NODES) return;
    int deg = cnt[node];
    int start = cursor[node] - deg;   // cursor holds end after fill
    float sx = 0.f, sy = 0.f;
    for (int base = 0; base < deg; base += 64) {
        int n = min(deg - base, 64);
        int idx = (lane < n) ? ssrc[start + base + lane] : 0;
        int j = 0;
        for (; j + 1 < n; j += 2) {
            int s0 = __shfl(idx, j), s1 = __shfl(idx, j + 1);
            if (lane < 58) {
                float2 v0 = *(const float2*)(x + (long)s0 * NROI + 2 * lane);
                float2 v1 = *(const float2*)(x + (long)s1 * NROI + 2 * lane);
                sx += v0.x + v1.x;
                sy += v0.y + v1.y;
            }
        }
        if (j < n) {
            int s0 = __shfl(idx, j);
            if (lane < 58) {
                float2 v0 = *(const float2*)(x + (long)s0 * NROI + 2 * lane);
                sx += v0.x;
                sy += v0.y;
            }
        }
    }
    float inv = 1.f / fmaxf((float)deg, 1.f);
    __hip_bfloat16* row = Ac1 + (long)node * 256;
    if (lane < 58) {
        row[2 * lane]           = __float2bfloat16(sx * inv);
        row[2 * lane + 1]       = __float2bfloat16(sy * inv);
        float2 xv = *(const float2*)(x + (long)node * NROI + 2 * lane);
        row[NROI + 2 * lane]     = __float2bfloat16(xv.x);
        row[NROI + 2 * lane + 1] = __float2bfloat16(xv.y);
    } else {
        int base = 2 * NROI + (lane - 58) * 4;   // 232..255, 6 lanes x 4
#pragma unroll
        for (int i = 0; i < 4; i++) row[base + i] = __float2bfloat16(0.f);
    }
}

// --- conv2 aggregation by gather on projected bf16 messages ------------------
__global__ __launch_bounds__(256) void gather2_kernel(
    const int* __restrict__ ssrc, const int* __restrict__ cursor,
    const int* __restrict__ cnt, const __hip_bfloat16* __restrict__ q,
    const float* __restrict__ b2, __hip_bfloat16* __restrict__ h2bf) {
    int node = blockIdx.x * 4 + (threadIdx.x >> 6);
    int lane = threadIdx.x & 63;
    if (node >= N_NODES) return;
    int deg = cnt[node];
    int start = cursor[node] - deg;
    float s = 0.f;
    for (int base = 0; base < deg; base += 64) {
        int n = min(deg - base, 64);
        int idx = (lane < n) ? ssrc[start + base + lane] : 0;
        int j = 0;
        for (; j + 1 < n; j += 2) {
            int s0 = __shfl(idx, j), s1 = __shfl(idx, j + 1);
            float v0 = __bfloat162float(q[(long)s0 * 128 + lane]);
            float v1 = __bfloat162float(q[(long)s1 * 128 + lane]);
            s += v0 + v1;
        }
        if (j < n) {
            int s0 = __shfl(idx, j);
            s += __bfloat162float(q[(long)s0 * 128 + lane]);
        }
    }
    float c = fmaxf((float)deg, 1.f);
    float qr = __bfloat162float(q[(long)node * 128 + 64 + lane]);
    float v = s / c + qr + b2[lane];
    h2bf[(long)node * HID + lane] = __float2bfloat16(mishf(v));
}

// --- unified conv MFMA GEMM: C[M][128] = act(A[M][Kpad] @ BT^T + bias) -------
// A bf16 row-major (k contig, Kpad mult of 32); BT bf16 [128][Kpad] (zero-padded);
// single 128-col tile, grid.x = M/128 row tiles, 4 waves x 64x64 quadrants.
__global__ __launch_bounds__(256) void conv_mfma_kernel(
    const __hip_bfloat16* __restrict__ Abf, int Kpad,
    const __hip_bfloat16* __restrict__ BT,
    const float* __restrict__ bias,
    __hip_bfloat16* __restrict__ C, int act) {
    __shared__ short As[128][40];
    __shared__ short Bs[128][40];
    const int t = threadIdx.x;
    const long row0 = (long)blockIdx.x * 128;

    const int sr = t >> 2;
    const int sc = (t & 3) << 3;
    const short* Ap = (const short*)Abf + (row0 + sr) * Kpad + sc;
    const short* Bp = (const short*)BT + sr * Kpad + sc;

    s16x8 ra0 = *(const s16x8*)(Ap);
    s16x8 ra1 = *(const s16x8*)(Ap + 64 * (long)Kpad);
    s16x8 rb0 = *(const s16x8*)(Bp);
    s16x8 rb1 = *(const s16x8*)(Bp + 64 * Kpad);

    const int lane = t & 63;
    const int wid = t >> 6;
    const int wr = (wid >> 1) << 6;
    const int wc = (wid & 1) << 6;
    const int fm = lane & 15;
    const int fk = (lane >> 4) << 3;

    f32x4 acc[4][4];
#pragma unroll
    for (int i = 0; i < 4; i++)
#pragma unroll
        for (int j = 0; j < 4; j++) acc[i][j] = (f32x4){0.f, 0.f, 0.f, 0.f};

    for (int k0 = 0; k0 < Kpad; k0 += 32) {
        *(s16x8*)&As[sr][sc] = ra0;
        *(s16x8*)&As[sr + 64][sc] = ra1;
        *(s16x8*)&Bs[sr][sc] = rb0;
        *(s16x8*)&Bs[sr + 64][sc] = rb1;
        __syncthreads();
        if (k0 + 32 < Kpad) {
            ra0 = *(const s16x8*)(Ap + k0 + 32);
            ra1 = *(const s16x8*)(Ap + 64 * (long)Kpad + k0 + 32);
            rb0 = *(const s16x8*)(Bp + k0 + 32);
            rb1 = *(const s16x8*)(Bp + 64 * Kpad + k0 + 32);
        }
        s16x8 a[4], b[4];
#pragma unroll
        for (int i = 0; i < 4; i++) a[i] = *(const s16x8*)&As[wr + i * 16 + fm][fk];
#pragma unroll
        for (int j = 0; j < 4; j++) b[j] = *(const s16x8*)&Bs[wc + j * 16 + fm][fk];
#pragma unroll
        for (int i = 0; i < 4; i++)
#pragma unroll
            for (int j = 0; j < 4; j++)
                acc[i][j] = __builtin_amdgcn_mfma_f32_16x16x32_bf16(
                    a[i], b[j], acc[i][j], 0, 0, 0);
        __syncthreads();
    }

#pragma unroll
    for (int i = 0; i < 4; i++) {
#pragma unroll
        for (int j = 0; j < 4; j++) {
            int gc = wc + j * 16 + fm;
            float bv = bias ? bias[gc] : 0.f;
#pragma unroll
            for (int r = 0; r < 4; r++) {
                long gr = row0 + wr + i * 16 + ((lane >> 4) << 2) + r;
                float v = acc[i][j][r] + bv;
                if (act) v = mishf(v);
                C[gr * 128 + gc] = __float2bfloat16(v);
            }
        }
    }
}

// --- tiled transpose + fp32->bf16: W[7424][3712] -> WT[3712][7424] -----------
__global__ __launch_bounds__(256) void transpose_bf16_kernel(
    const float* __restrict__ W, __hip_bfloat16* __restrict__ WT) {
    __shared__ float tile[32][33];
    const int t = threadIdx.x;
    const int tn = t & 31, tk = t >> 5;
    const int n0 = blockIdx.x * 32;
    const int k0 = blockIdx.y * 32;
#pragma unroll
    for (int i = 0; i < 4; i++) {
        tile[tk + i * 8][tn] = W[(long)(k0 + tk + i * 8) * D1 + (n0 + tn)];
    }
    __syncthreads();
#pragma unroll
    for (int i = 0; i < 4; i++) {
        int n = n0 + tk + i * 8;
        int k = k0 + tn;
        WT[(long)n * KDIM + k] = __float2bfloat16(tile[tn][tk + i * 8]);
    }
}

// --- lin1 via bf16 MFMA: C[1024][3712] = A[1024][7424] @ B + bias ------------
__global__ __launch_bounds__(256) void lin1_mfma_kernel(
    const __hip_bfloat16* __restrict__ Abf,
    const __hip_bfloat16* __restrict__ BTbf,
    const float* __restrict__ bias,
    float* __restrict__ C) {
    __shared__ short As[128][40];
    __shared__ short Bs[128][40];
    const int t = threadIdx.x;
    const long row0 = (long)blockIdx.y * 128;
    const long col0 = (long)blockIdx.x * 128;

    const int sr = t >> 2;
    const int sc = (t & 3) << 3;
    const short* Ap = (const short*)Abf + (row0 + sr) * KDIM + sc;
    const short* Bp = (const short*)BTbf + (col0 + sr) * KDIM + sc;

    s16x8 ra0 = *(const s16x8*)(Ap);
    s16x8 ra1 = *(const s16x8*)(Ap + 64 * KDIM);
    s16x8 rb0 = *(const s16x8*)(Bp);
    s16x8 rb1 = *(const s16x8*)(Bp + 64 * KDIM);

    const int lane = t & 63;
    const int wid = t >> 6;
    const int wr = (wid >> 1) << 6;
    const int wc = (wid & 1) << 6;
    const int fm = lane & 15;
    const int fk = (lane >> 4) << 3;

    f32x4 acc[4][4];
#pragma unroll
    for (int i = 0; i < 4; i++)
#pragma unroll
        for (int j = 0; j < 4; j++) acc[i][j] = (f32x4){0.f, 0.f, 0.f, 0.f};

    for (int k0 = 0; k0 < KDIM; k0 += 32) {
        *(s16x8*)&As[sr][sc] = ra0;
        *(s16x8*)&As[sr + 64][sc] = ra1;
        *(s16x8*)&Bs[sr][sc] = rb0;
        *(s16x8*)&Bs[sr + 64][sc] = rb1;
        __syncthreads();
        if (k0 + 32 < KDIM) {
            ra0 = *(const s16x8*)(Ap + k0 + 32);
            ra1 = *(const s16x8*)(Ap + 64 * KDIM + k0 + 32);
            rb0 = *(const s16x8*)(Bp + k0 + 32);
            rb1 = *(const s16x8*)(Bp + 64 * KDIM + k0 + 32);
        }
        s16x8 a[4], b[4];
#pragma unroll
        for (int i = 0; i < 4; i++) a[i] = *(const s16x8*)&As[wr + i * 16 + fm][fk];
#pragma unroll
        for (int j = 0; j < 4; j++) b[j] = *(const s16x8*)&Bs[wc + j * 16 + fm][fk];
#pragma unroll
        for (int i = 0; i < 4; i++)
#pragma unroll
            for (int j = 0; j < 4; j++)
                acc[i][j] = __builtin_amdgcn_mfma_f32_16x16x32_bf16(
                    a[i], b[j], acc[i][j], 0, 0, 0);
        __syncthreads();
    }

#pragma unroll
    for (int i = 0; i < 4; i++) {
#pragma unroll
        for (int j = 0; j < 4; j++) {
            int gc = (int)col0 + wc + j * 16 + fm;
            float bv = bias[gc];
#pragma unroll
            for (int r = 0; r < 4; r++) {
                long gr = row0 + wr + i * 16 + ((lane >> 4) << 2) + r;
                C[gr * D1 + gc] = acc[i][j][r] + bv;
            }
        }
    }
}

// --- fused layernorm + mish + lin2 tail --------------------------------------
__global__ __launch_bounds__(256) void tail_kernel(
    const float* __restrict__ t1, const float* __restrict__ g,
    const float* __restrict__ b, const float* __restrict__ w2,
    const float* __restrict__ b2, float* __restrict__ out) {
    int row = blockIdx.x;
    const float* h = t1 + (long)row * D1;
    int t = threadIdx.x;
    int w = t >> 6, lane = t & 63;
    float s = 0.f, ss = 0.f;
    for (int i = t; i < D1; i += 256) {
        float v = h[i];
        s += v;
        ss += v * v;
    }
    for (int d = 32; d > 0; d >>= 1) {
        s += __shfl_down(s, d);
        ss += __shfl_down(ss, d);
    }
    __shared__ float sh[8];
    if (lane == 0) { sh[w] = s; sh[4 + w] = ss; }
    __syncthreads();
    if (t == 0) {
        sh[0] = sh[0] + sh[1] + sh[2] + sh[3];
        sh[4] = sh[4] + sh[5] + sh[6] + sh[7];
    }
    __syncthreads();
    float mu = sh[0] * (1.f / D1);
    float var = sh[4] * (1.f / D1) - mu * mu;
    float rs = rsqrtf(var + 1e-5f);
    float d0 = 0.f, d1 = 0.f;
    for (int i = t; i < D1; i += 256) {
        float v = (h[i] - mu) * rs * g[i] + b[i];
        v = mishf(v);
        d0 += v * w2[2 * i];
        d1 += v * w2[2 * i + 1];
    }
    for (int d = 32; d > 0; d >>= 1) {
        d0 += __shfl_down(d0, d);
        d1 += __shfl_down(d1, d);
    }
    __shared__ float sh2[8];
    if (lane == 0) { sh2[w] = d0; sh2[4 + w] = d1; }
    __syncthreads();
    if (t == 0) {
        out[2 * row] = sh2[0] + sh2[1] + sh2[2] + sh2[3] + b2[0];
        out[2 * row + 1] = sh2[4] + sh2[5] + sh2[6] + sh2[7] + b2[1];
    }
}

extern "C" void kernel_launch(void* const* d_in, const int* in_sizes, int n_in,
                              void* d_out, int out_size, void* d_ws, size_t ws_size,
                              hipStream_t stream) {
    const float* x      = (const float*)d_in[0];
    const int*   ei     = (const int*)d_in[1];
    const float* w1_l   = (const float*)d_in[2];
    const float* b1     = (const float*)d_in[3];
    const float* w1_r   = (const float*)d_in[4];
    const float* w2_l   = (const float*)d_in[5];
    const float* b2     = (const float*)d_in[6];
    const float* w2_r   = (const float*)d_in[7];
    const float* w_lin1 = (const float*)d_in[8];
    const float* b_lin1 = (const float*)d_in[9];
    const float* ln_g   = (const float*)d_in[10];
    const float* ln_b   = (const float*)d_in[11];
    const float* w_lin2 = (const float*)d_in[12];
    const float* b_lin2 = (const float*)d_in[13];
    float* out = (float*)d_out;

    char* ws = (char*)d_ws;
    // workspace layout (bytes), liveness-based reuse (max ~160.7MB, <171.7 proven):
    //   [0,          60,817,408)  Ac1 bf16 [N][256] (gather1->conv1)
    //                             -> wT bf16 [3712][7424] (transpose->lin1, Ac1 dead)
    //   [60,817,408, 91,226,112)  h1b bf16 [N][128] (conv1->conv2)
    //   [91,226,112, 121,634,816) q bf16 [N][128] (conv2->gather2)
    //   [121,634,816,136,839,168) t1 fp32 [1024][3712] (lin1->tail)
    //   [136,839,168,137,314,304) cnt int[N]
    //   [137,314,304,137,789,440) cursor int[N]
    //   [137,789,440,137,791,488) bsum int[512]
    //   [137,791,488,145,393,664) ssrc int[E]
    //   [145,393,664,160,598,016) h2bf bf16 [N][64] (gather2->lin1)
    //   [160,598,016,160,663,552) BT1 bf16 [128][256]
    //   [160,663,552,160,664,064) bias1p fp32[128]
    //   [160,664,064,160,696,832) BT2 bf16 [128][128]
    __hip_bfloat16* Ac1   = (__hip_bfloat16*)(ws + 0);
    __hip_bfloat16* wT    = (__hip_bfloat16*)(ws + 0);
    __hip_bfloat16* h1b   = (__hip_bfloat16*)(ws + 60817408);
    __hip_bfloat16* q     = (__hip_bfloat16*)(ws + 91226112);
    float* t1             = (float*)(ws + 121634816);
    int*   cnt            = (int*)(ws + 136839168);
    int*   cursor         = (int*)(ws + 137314304);
    int*   bsum           = (int*)(ws + 137789440);
    int*   ssrc           = (int*)(ws + 137791488);
    __hip_bfloat16* h2bf  = (__hip_bfloat16*)(ws + 145393664);
    __hip_bfloat16* BT1   = (__hip_bfloat16*)(ws + 160598016);
    float* bias1p         = (float*)(ws + 160663552);
    __hip_bfloat16* BT2   = (__hip_bfloat16*)(ws + 160664064);

    const int* src = ei;
    const int* dst = ei + N_EDGES;

    const int NB = N_NODES / 256;          // 464 scan blocks
    const int EB = (N_EDGES + 255) / 256;  // edge-grid blocks

    // --- CSR build ---
    hipMemsetAsync(cnt, 0, N_NODES * sizeof(int), stream);
    hist_kernel<<<EB, 256, 0, stream>>>(dst, cnt);
    scan1_kernel<<<NB, 256, 0, stream>>>(cnt, cursor, bsum);
    scan2_kernel<<<1, 512, 0, stream>>>(bsum, NB);
    scan3_kernel<<<NB, 256, 0, stream>>>(cursor, bsum);
    fill_kernel<<<EB, 256, 0, stream>>>(src, dst, cursor, ssrc);

    // --- padded bf16 weights ---
    concat1_kernel<<<(128 * 256 + 255) / 256, 256, 0, stream>>>(w1_l, w1_r, b1, BT1, bias1p);
    concat2_kernel<<<(128 * 128 + 255) / 256, 256, 0, stream>>>(w2_l, w2_r, BT2);

    // --- conv1: gather-mean (packed bf16 A) then MFMA GEMM ---
    gather1_kernel<<<(N_NODES + 3) / 4, 256, 0, stream>>>(ssrc, cursor, cnt, x, Ac1);
    conv_mfma_kernel<<<N_NODES / 128, 256, 0, stream>>>(Ac1, 256, BT1, bias1p, h1b, 1);

    // --- conv2: project first (q = h1 @ [w2_l|w2_r]), gather, combine ---
    conv_mfma_kernel<<<N_NODES / 128, 256, 0, stream>>>(h1b, 128, BT2, nullptr, q, 0);
    gather2_kernel<<<(N_NODES + 3) / 4, 256, 0, stream>>>(ssrc, cursor, cnt, q, b2, h2bf);

    // --- lin1 (bf16 MFMA); wT overlaps dead Ac1 ---
    transpose_bf16_kernel<<<dim3(D1 / 32, KDIM / 32), 256, 0, stream>>>(w_lin1, wT);
    lin1_mfma_kernel<<<dim3(D1 / 128, BATCH / 128), 256, 0, stream>>>(h2bf, wT, b_lin1, t1);

    // --- layernorm + mish + lin2 ---
    tail_kernel<<<BATCH, 256, 0, stream>>>(t1, ln_g, ln_b, w_lin2, b_lin2, out);
}

// Round 5
// 806.415 us; speedup vs baseline: 3.8939x; 1.1151x over previous
//
#include <hip/hip_runtime.h>
#include <hip/hip_bf16.h>
#include <cstdint>

#define N_NODES 118784
#define N_EDGES 1900544
#define NROI 116
#define HID 64
#define D1 3712
#define BATCH 1024
#define KDIM 7424   // N_ROI * HIDDEN

typedef __attribute__((ext_vector_type(8))) short s16x8;
typedef __attribute__((ext_vector_type(4))) float f32x4;

__device__ __forceinline__ float mishf(float x) {
    if (x > 20.f) return x;
    float e = __expf(x);
    float n = e * e + 2.f * e;
    return x * n / (n + 2.f);
}

// --- build BT1 [128][256] bf16 (padded [w1_l; w1_r]^T) + bias1p[128] ---------
__global__ void concat1_kernel(const float* __restrict__ w1_l,
                               const float* __restrict__ w1_r,
                               const float* __restrict__ b1,
                               __hip_bfloat16* __restrict__ BT1,
                               float* __restrict__ bias1p) {
    int idx = blockIdx.x * 256 + threadIdx.x;
    if (idx >= 128 * 256) return;
    int j = idx >> 8, k = idx & 255;
    float v = 0.f;
    if (j < NROI) {
        if (k < NROI) v = w1_l[k * NROI + j];
        else if (k < 2 * NROI) v = w1_r[(k - NROI) * NROI + j];
    }
    BT1[idx] = __float2bfloat16(v);
    if (idx < 128) bias1p[idx] = (idx < NROI) ? b1[idx] : 0.f;
}

// --- build BT2 [128][128] bf16 (padded [w2_l | w2_r]^T) ----------------------
__global__ void concat2_kernel(const float* __restrict__ w2_l,
                               const float* __restrict__ w2_r,
                               __hip_bfloat16* __restrict__ BT2) {
    int idx = blockIdx.x * 256 + threadIdx.x;
    if (idx >= 128 * 128) return;
    int j = idx >> 7, k = idx & 127;
    float v = 0.f;
    if (k < NROI) v = (j < HID) ? w2_l[k * HID + j] : w2_r[k * HID + (j - HID)];
    BT2[idx] = __float2bfloat16(v);
}

// --- x fp32 -> xb bf16 (row-major [N][116]) ----------------------------------
__global__ void xconv_kernel(const float* __restrict__ x,
                             __hip_bfloat16* __restrict__ xb) {
    long i = (long)blockIdx.x * 256 + threadIdx.x;   // one thread per 2 elems
    if (i >= (long)N_NODES * 58) return;
    float2 v = *(const float2*)(x + 2 * i);
    __hip_bfloat162 o;
    o.x = __float2bfloat16(v.x);
    o.y = __float2bfloat16(v.y);
    *(__hip_bfloat162*)((__hip_bfloat16*)xb + 2 * i) = o;
}

// --- CSR build: histogram -> exclusive scan -> cursor fill -------------------
__global__ void hist_kernel(const int* __restrict__ dst, int* __restrict__ cnt) {
    int e = blockIdx.x * 256 + threadIdx.x;
    if (e < N_EDGES) atomicAdd(&cnt[dst[e]], 1);
}

__global__ __launch_bounds__(256) void scan1_kernel(const int* __restrict__ cnt,
                                                    int* __restrict__ cursor,
                                                    int* __restrict__ bsum) {
    __shared__ int sh[256];
    int t = threadIdx.x;
    int i = blockIdx.x * 256 + t;
    int v = cnt[i];
    sh[t] = v;
    __syncthreads();
    for (int d = 1; d < 256; d <<= 1) {
        int a = (t >= d) ? sh[t - d] : 0;
        __syncthreads();
        sh[t] += a;
        __syncthreads();
    }
    cursor[i] = sh[t] - v;
    if (t == 255) bsum[blockIdx.x] = sh[255];
}

__global__ __launch_bounds__(512) void scan2_kernel(int* __restrict__ bsum, int nb) {
    __shared__ int sh[512];
    int t = threadIdx.x;
    int v = (t < nb) ? bsum[t] : 0;
    sh[t] = v;
    __syncthreads();
    for (int d = 1; d < 512; d <<= 1) {
        int a = (t >= d) ? sh[t - d] : 0;
        __syncthreads();
        sh[t] += a;
        __syncthreads();
    }
    if (t < nb) bsum[t] = sh[t] - v;
}

__global__ void scan3_kernel(int* __restrict__ cursor, const int* __restrict__ bsum) {
    int i = blockIdx.x * 256 + threadIdx.x;
    cursor[i] += bsum[blockIdx.x];
}

__global__ void fill_kernel(const int* __restrict__ src, const int* __restrict__ dst,
                            int* __restrict__ cursor, int* __restrict__ ssrc) {
    int e = blockIdx.x * 256 + threadIdx.x;
    if (e >= N_EDGES) return;
    int d = dst[e];
    int pos = atomicAdd(&cursor[d], 1);
    ssrc[pos] = src[e];
}

// --- conv1 aggregation by gather on bf16 x, emitting packed bf16 A-matrix ----
// Ac1[n] = [ bf16(mean_{j in N(n)} xb[j]) (116) | xb[n] (116) | 0 (24) ]
__global__ __launch_bounds__(256) void gather1_kernel(
    const int* __restrict__ ssrc, const int* __restrict__ cursor,
    const int* __restrict__ cnt, const __hip_bfloat16* __restrict__ xb,
    __hip_bfloat16* __restrict__ Ac1) {
    int node = blockIdx.x * 4 + (threadIdx.x >> 6);
    int lane = threadIdx.x & 63;
    if (node >= N_NODES) return;
    int deg = cnt[node];
    int start = cursor[node] - deg;   // cursor holds end after fill
    float sx = 0.f, sy = 0.f;
    const unsigned short* xbs = (const unsigned short*)xb;
    for (int base = 0; base < deg; base += 64) {
        int n = min(deg - base, 64);
        int idx = (lane < n) ? ssrc[start + base + lane] : 0;
        int j = 0;
        for (; j + 3 < n; j += 4) {
            int s0 = __shfl(idx, j), s1 = __shfl(idx, j + 1);
            int s2 = __shfl(idx, j + 2), s3 = __shfl(idx, j + 3);
            if (lane < 58) {
                unsigned int u0 = *(const unsigned int*)(xbs + (long)s0 * NROI + 2 * lane);
                unsigned int u1 = *(const unsigned int*)(xbs + (long)s1 * NROI + 2 * lane);
                unsigned int u2 = *(const unsigned int*)(xbs + (long)s2 * NROI + 2 * lane);
                unsigned int u3 = *(const unsigned int*)(xbs + (long)s3 * NROI + 2 * lane);
                sx += __uint_as_float(u0 << 16) + __uint_as_float(u1 << 16)
                    + __uint_as_float(u2 << 16) + __uint_as_float(u3 << 16);
                sy += __uint_as_float(u0 & 0xFFFF0000u) + __uint_as_float(u1 & 0xFFFF0000u)
                    + __uint_as_float(u2 & 0xFFFF0000u) + __uint_as_float(u3 & 0xFFFF0000u);
            }
        }
        for (; j < n; j++) {
            int s0 = __shfl(idx, j);
            if (lane < 58) {
                unsigned int u0 = *(const unsigned int*)(xbs + (long)s0 * NROI + 2 * lane);
                sx += __uint_as_float(u0 << 16);
                sy += __uint_as_float(u0 & 0xFFFF0000u);
            }
        }
    }
    float inv = 1.f / fmaxf((float)deg, 1.f);
    __hip_bfloat16* row = Ac1 + (long)node * 256;
    if (lane < 58) {
        __hip_bfloat162 m2;
        m2.x = __float2bfloat16(sx * inv);
        m2.y = __float2bfloat16(sy * inv);
        *(__hip_bfloat162*)(row + 2 * lane) = m2;
        // self row: straight bf16 copy
        unsigned int u = *(const unsigned int*)(xbs + (long)node * NROI + 2 * lane);
        *(unsigned int*)(row + NROI + 2 * lane) = u;
    } else {
        int base = 2 * NROI + (lane - 58) * 4;   // 232..255, 6 lanes x 4
        *(unsigned int*)(row + base) = 0u;
        *(unsigned int*)(row + base + 2) = 0u;
    }
}

// --- conv2 aggregation by gather on projected bf16 messages ------------------
__global__ __launch_bounds__(256) void gather2_kernel(
    const int* __restrict__ ssrc, const int* __restrict__ cursor,
    const int* __restrict__ cnt, const __hip_bfloat16* __restrict__ q,
    const float* __restrict__ b2, __hip_bfloat16* __restrict__ h2bf) {
    int node = blockIdx.x * 4 + (threadIdx.x >> 6);
    int lane = threadIdx.x & 63;
    if (node >= N_NODES) return;
    int deg = cnt[node];
    int start = cursor[node] - deg;
    float s = 0.f;
    for (int base = 0; base < deg; base += 64) {
        int n = min(deg - base, 64);
        int idx = (lane < n) ? ssrc[start + base + lane] : 0;
        int j = 0;
        for (; j + 3 < n; j += 4) {
            int s0 = __shfl(idx, j), s1 = __shfl(idx, j + 1);
            int s2 = __shfl(idx, j + 2), s3 = __shfl(idx, j + 3);
            float v0 = __bfloat162float(q[(long)s0 * 128 + lane]);
            float v1 = __bfloat162float(q[(long)s1 * 128 + lane]);
            float v2 = __bfloat162float(q[(long)s2 * 128 + lane]);
            float v3 = __bfloat162float(q[(long)s3 * 128 + lane]);
            s += (v0 + v1) + (v2 + v3);
        }
        for (; j < n; j++) {
            int s0 = __shfl(idx, j);
            s += __bfloat162float(q[(long)s0 * 128 + lane]);
        }
    }
    float c = fmaxf((float)deg, 1.f);
    float qr = __bfloat162float(q[(long)node * 128 + 64 + lane]);
    float v = s / c + qr + b2[lane];
    h2bf[(long)node * HID + lane] = __float2bfloat16(mishf(v));
}

// --- unified conv MFMA GEMM: C[M][128] = act(A[M][Kpad] @ BT^T + bias) -------
__global__ __launch_bounds__(256) void conv_mfma_kernel(
    const __hip_bfloat16* __restrict__ Abf, int Kpad,
    const __hip_bfloat16* __restrict__ BT,
    const float* __restrict__ bias,
    __hip_bfloat16* __restrict__ C, int act) {
    __shared__ short As[128][40];
    __shared__ short Bs[128][40];
    const int t = threadIdx.x;
    const long row0 = (long)blockIdx.x * 128;

    const int sr = t >> 2;
    const int sc = (t & 3) << 3;
    const short* Ap = (const short*)Abf + (row0 + sr) * Kpad + sc;
    const short* Bp = (const short*)BT + sr * Kpad + sc;

    s16x8 ra0 = *(const s16x8*)(Ap);
    s16x8 ra1 = *(const s16x8*)(Ap + 64 * (long)Kpad);
    s16x8 rb0 = *(const s16x8*)(Bp);
    s16x8 rb1 = *(const s16x8*)(Bp + 64 * Kpad);

    const int lane = t & 63;
    const int wid = t >> 6;
    const int wr = (wid >> 1) << 6;
    const int wc = (wid & 1) << 6;
    const int fm = lane & 15;
    const int fk = (lane >> 4) << 3;

    f32x4 acc[4][4];
#pragma unroll
    for (int i = 0; i < 4; i++)
#pragma unroll
        for (int j = 0; j < 4; j++) acc[i][j] = (f32x4){0.f, 0.f, 0.f, 0.f};

    for (int k0 = 0; k0 < Kpad; k0 += 32) {
        *(s16x8*)&As[sr][sc] = ra0;
        *(s16x8*)&As[sr + 64][sc] = ra1;
        *(s16x8*)&Bs[sr][sc] = rb0;
        *(s16x8*)&Bs[sr + 64][sc] = rb1;
        __syncthreads();
        if (k0 + 32 < Kpad) {
            ra0 = *(const s16x8*)(Ap + k0 + 32);
            ra1 = *(const s16x8*)(Ap + 64 * (long)Kpad + k0 + 32);
            rb0 = *(const s16x8*)(Bp + k0 + 32);
            rb1 = *(const s16x8*)(Bp + 64 * Kpad + k0 + 32);
        }
        s16x8 a[4], b[4];
#pragma unroll
        for (int i = 0; i < 4; i++) a[i] = *(const s16x8*)&As[wr + i * 16 + fm][fk];
#pragma unroll
        for (int j = 0; j < 4; j++) b[j] = *(const s16x8*)&Bs[wc + j * 16 + fm][fk];
#pragma unroll
        for (int i = 0; i < 4; i++)
#pragma unroll
            for (int j = 0; j < 4; j++)
                acc[i][j] = __builtin_amdgcn_mfma_f32_16x16x32_bf16(
                    a[i], b[j], acc[i][j], 0, 0, 0);
        __syncthreads();
    }

#pragma unroll
    for (int i = 0; i < 4; i++) {
#pragma unroll
        for (int j = 0; j < 4; j++) {
            int gc = wc + j * 16 + fm;
            float bv = bias ? bias[gc] : 0.f;
#pragma unroll
            for (int r = 0; r < 4; r++) {
                long gr = row0 + wr + i * 16 + ((lane >> 4) << 2) + r;
                float v = acc[i][j][r] + bv;
                if (act) v = mishf(v);
                C[gr * 128 + gc] = __float2bfloat16(v);
            }
        }
    }
}

// --- tiled transpose + fp32->bf16: W[7424][3712] -> WT[3712][7424] -----------
__global__ __launch_bounds__(256) void transpose_bf16_kernel(
    const float* __restrict__ W, __hip_bfloat16* __restrict__ WT) {
    __shared__ float tile[32][33];
    const int t = threadIdx.x;
    const int tn = t & 31, tk = t >> 5;
    const int n0 = blockIdx.x * 32;
    const int k0 = blockIdx.y * 32;
#pragma unroll
    for (int i = 0; i < 4; i++) {
        tile[tk + i * 8][tn] = W[(long)(k0 + tk + i * 8) * D1 + (n0 + tn)];
    }
    __syncthreads();
#pragma unroll
    for (int i = 0; i < 4; i++) {
        int n = n0 + tk + i * 8;
        int k = k0 + tn;
        WT[(long)n * KDIM + k] = __float2bfloat16(tile[tn][tk + i * 8]);
    }
}

// --- lin1 via bf16 MFMA, XCD-swizzled grid -----------------------------------
// Grid: 256 linear blocks -> (col 0..28, row 0..7); all 8 row-blocks of a col
// share id%8 so they land on the same XCD and share the B stripe in its L2.
__global__ __launch_bounds__(256) void lin1_mfma_kernel(
    const __hip_bfloat16* __restrict__ Abf,
    const __hip_bfloat16* __restrict__ BTbf,
    const float* __restrict__ bias,
    float* __restrict__ C) {
    __shared__ short As[128][40];
    __shared__ short Bs[128][40];
    const int t = threadIdx.x;
    const int id = blockIdx.x;
    const int xx = id & 7, yy = id >> 3;       // yy 0..31
    const int col = xx + 8 * (yy & 3);         // 0..31
    const int row = yy >> 2;                   // 0..7
    if (col >= D1 / 128) return;               // 29 cols; 24 dead blocks
    const long row0 = (long)row * 128;
    const long col0 = (long)col * 128;

    const int sr = t >> 2;
    const int sc = (t & 3) << 3;
    const short* Ap = (const short*)Abf + (row0 + sr) * KDIM + sc;
    const short* Bp = (const short*)BTbf + (col0 + sr) * KDIM + sc;

    s16x8 ra0 = *(const s16x8*)(Ap);
    s16x8 ra1 = *(const s16x8*)(Ap + 64 * KDIM);
    s16x8 rb0 = *(const s16x8*)(Bp);
    s16x8 rb1 = *(const s16x8*)(Bp + 64 * KDIM);

    const int lane = t & 63;
    const int wid = t >> 6;
    const int wr = (wid >> 1) << 6;
    const int wc = (wid & 1) << 6;
    const int fm = lane & 15;
    const int fk = (lane >> 4) << 3;

    f32x4 acc[4][4];
#pragma unroll
    for (int i = 0; i < 4; i++)
#pragma unroll
        for (int j = 0; j < 4; j++) acc[i][j] = (f32x4){0.f, 0.f, 0.f, 0.f};

    for (int k0 = 0; k0 < KDIM; k0 += 32) {
        *(s16x8*)&As[sr][sc] = ra0;
        *(s16x8*)&As[sr + 64][sc] = ra1;
        *(s16x8*)&Bs[sr][sc] = rb0;
        *(s16x8*)&Bs[sr + 64][sc] = rb1;
        __syncthreads();
        if (k0 + 32 < KDIM) {
            ra0 = *(const s16x8*)(Ap + k0 + 32);
            ra1 = *(const s16x8*)(Ap + 64 * KDIM + k0 + 32);
            rb0 = *(const s16x8*)(Bp + k0 + 32);
            rb1 = *(const s16x8*)(Bp + 64 * KDIM + k0 + 32);
        }
        s16x8 a[4], b[4];
#pragma unroll
        for (int i = 0; i < 4; i++) a[i] = *(const s16x8*)&As[wr + i * 16 + fm][fk];
#pragma unroll
        for (int j = 0; j < 4; j++) b[j] = *(const s16x8*)&Bs[wc + j * 16 + fm][fk];
#pragma unroll
        for (int i = 0; i < 4; i++)
#pragma unroll
            for (int j = 0; j < 4; j++)
                acc[i][j] = __builtin_amdgcn_mfma_f32_16x16x32_bf16(
                    a[i], b[j], acc[i][j], 0, 0, 0);
        __syncthreads();
    }

#pragma unroll
    for (int i = 0; i < 4; i++) {
#pragma unroll
        for (int j = 0; j < 4; j++) {
            int gc = (int)col0 + wc + j * 16 + fm;
            float bv = bias[gc];
#pragma unroll
            for (int r = 0; r < 4; r++) {
                long gr = row0 + wr + i * 16 + ((lane >> 4) << 2) + r;
                C[gr * D1 + gc] = acc[i][j][r] + bv;
            }
        }
    }
}

// --- fused layernorm + mish + lin2 tail --------------------------------------
__global__ __launch_bounds__(256) void tail_kernel(
    const float* __restrict__ t1, const float* __restrict__ g,
    const float* __restrict__ b, const float* __restrict__ w2,
    const float* __restrict__ b2, float* __restrict__ out) {
    int row = blockIdx.x;
    const float* h = t1 + (long)row * D1;
    int t = threadIdx.x;
    int w = t >> 6, lane = t & 63;
    float s = 0.f, ss = 0.f;
    for (int i = t; i < D1; i += 256) {
        float v = h[i];
        s += v;
        ss += v * v;
    }
    for (int d = 32; d > 0; d >>= 1) {
        s += __shfl_down(s, d);
        ss += __shfl_down(ss, d);
    }
    __shared__ float sh[8];
    if (lane == 0) { sh[w] = s; sh[4 + w] = ss; }
    __syncthreads();
    if (t == 0) {
        sh[0] = sh[0] + sh[1] + sh[2] + sh[3];
        sh[4] = sh[4] + sh[5] + sh[6] + sh[7];
    }
    __syncthreads();
    float mu = sh[0] * (1.f / D1);
    float var = sh[4] * (1.f / D1) - mu * mu;
    float rs = rsqrtf(var + 1e-5f);
    float d0 = 0.f, d1 = 0.f;
    for (int i = t; i < D1; i += 256) {
        float v = (h[i] - mu) * rs * g[i] + b[i];
        v = mishf(v);
        d0 += v * w2[2 * i];
        d1 += v * w2[2 * i + 1];
    }
    for (int d = 32; d > 0; d >>= 1) {
        d0 += __shfl_down(d0, d);
        d1 += __shfl_down(d1, d);
    }
    __shared__ float sh2[8];
    if (lane == 0) { sh2[w] = d0; sh2[4 + w] = d1; }
    __syncthreads();
    if (t == 0) {
        out[2 * row] = sh2[0] + sh2[1] + sh2[2] + sh2[3] + b2[0];
        out[2 * row + 1] = sh2[4] + sh2[5] + sh2[6] + sh2[7] + b2[1];
    }
}

extern "C" void kernel_launch(void* const* d_in, const int* in_sizes, int n_in,
                              void* d_out, int out_size, void* d_ws, size_t ws_size,
                              hipStream_t stream) {
    const float* x      = (const float*)d_in[0];
    const int*   ei     = (const int*)d_in[1];
    const float* w1_l   = (const float*)d_in[2];
    const float* b1     = (const float*)d_in[3];
    const float* w1_r   = (const float*)d_in[4];
    const float* w2_l   = (const float*)d_in[5];
    const float* b2     = (const float*)d_in[6];
    const float* w2_r   = (const float*)d_in[7];
    const float* w_lin1 = (const float*)d_in[8];
    const float* b_lin1 = (const float*)d_in[9];
    const float* ln_g   = (const float*)d_in[10];
    const float* ln_b   = (const float*)d_in[11];
    const float* w_lin2 = (const float*)d_in[12];
    const float* b_lin2 = (const float*)d_in[13];
    float* out = (float*)d_out;

    char* ws = (char*)d_ws;
    // workspace layout (bytes), liveness-based reuse (max ~160.7MB, <171.7 proven):
    //   [0,          60,817,408)  Ac1 bf16 [N][256] (gather1->conv1)
    //                             -> wT bf16 [3712][7424] (transpose->lin1, Ac1 dead)
    //   [60,817,408, 91,226,112)  h1b bf16 [N][128] (conv1->conv2)
    //   [91,226,112, 121,634,816) xb bf16 [N][116] (xconv->gather1, 27.6MB)
    //                             -> q bf16 [N][128] (conv2->gather2; xb dead)
    //   [121,634,816,136,839,168) t1 fp32 [1024][3712] (lin1->tail)
    //   [136,839,168,137,314,304) cnt int[N]
    //   [137,314,304,137,789,440) cursor int[N]
    //   [137,789,440,137,791,488) bsum int[512]
    //   [137,791,488,145,393,664) ssrc int[E]
    //   [145,393,664,160,598,016) h2bf bf16 [N][64] (gather2->lin1)
    //   [160,598,016,160,663,552) BT1 bf16 [128][256]
    //   [160,663,552,160,664,064) bias1p fp32[128]
    //   [160,664,064,160,696,832) BT2 bf16 [128][128]
    __hip_bfloat16* Ac1   = (__hip_bfloat16*)(ws + 0);
    __hip_bfloat16* wT    = (__hip_bfloat16*)(ws + 0);
    __hip_bfloat16* h1b   = (__hip_bfloat16*)(ws + 60817408);
    __hip_bfloat16* xb    = (__hip_bfloat16*)(ws + 91226112);
    __hip_bfloat16* q     = (__hip_bfloat16*)(ws + 91226112);
    float* t1             = (float*)(ws + 121634816);
    int*   cnt            = (int*)(ws + 136839168);
    int*   cursor         = (int*)(ws + 137314304);
    int*   bsum           = (int*)(ws + 137789440);
    int*   ssrc           = (int*)(ws + 137791488);
    __hip_bfloat16* h2bf  = (__hip_bfloat16*)(ws + 145393664);
    __hip_bfloat16* BT1   = (__hip_bfloat16*)(ws + 160598016);
    float* bias1p         = (float*)(ws + 160663552);
    __hip_bfloat16* BT2   = (__hip_bfloat16*)(ws + 160664064);

    const int* src = ei;
    const int* dst = ei + N_EDGES;

    const int NB = N_NODES / 256;          // 464 scan blocks
    const int EB = (N_EDGES + 255) / 256;  // edge-grid blocks

    // --- CSR build ---
    hipMemsetAsync(cnt, 0, N_NODES * sizeof(int), stream);
    hist_kernel<<<EB, 256, 0, stream>>>(dst, cnt);
    scan1_kernel<<<NB, 256, 0, stream>>>(cnt, cursor, bsum);
    scan2_kernel<<<1, 512, 0, stream>>>(bsum, NB);
    scan3_kernel<<<NB, 256, 0, stream>>>(cursor, bsum);
    fill_kernel<<<EB, 256, 0, stream>>>(src, dst, cursor, ssrc);

    // --- padded bf16 weights + bf16 x ---
    concat1_kernel<<<(128 * 256 + 255) / 256, 256, 0, stream>>>(w1_l, w1_r, b1, BT1, bias1p);
    concat2_kernel<<<(128 * 128 + 255) / 256, 256, 0, stream>>>(w2_l, w2_r, BT2);
    xconv_kernel<<<(int)(((long)N_NODES * 58 + 255) / 256), 256, 0, stream>>>(x, xb);

    // --- conv1: gather-mean (bf16 in, packed bf16 A out) then MFMA GEMM ---
    gather1_kernel<<<(N_NODES + 3) / 4, 256, 0, stream>>>(ssrc, cursor, cnt, xb, Ac1);
    conv_mfma_kernel<<<N_NODES / 128, 256, 0, stream>>>(Ac1, 256, BT1, bias1p, h1b, 1);

    // --- conv2: project first (q = h1 @ [w2_l|w2_r]), gather, combine ---
    // NOTE: q overwrites xb (dead after gather1).
    conv_mfma_kernel<<<N_NODES / 128, 256, 0, stream>>>(h1b, 128, BT2, nullptr, q, 0);
    gather2_kernel<<<(N_NODES + 3) / 4, 256, 0, stream>>>(ssrc, cursor, cnt, q, b2, h2bf);

    // --- lin1 (bf16 MFMA, XCD-swizzled); wT overlaps dead Ac1 ---
    transpose_bf16_kernel<<<dim3(D1 / 32, KDIM / 32), 256, 0, stream>>>(w_lin1, wT);
    lin1_mfma_kernel<<<256, 256, 0, stream>>>(h2bf, wT, b_lin1, t1);

    // --- layernorm + mish + lin2 ---
    tail_kernel<<<BATCH, 256, 0, stream>>>(t1, ln_g, ln_b, w_lin2, b_lin2, out);
}

// Round 6
// 671.873 us; speedup vs baseline: 4.6736x; 1.2002x over previous
//
#include <hip/hip_runtime.h>
#include <hip/hip_bf16.h>
#include <cstdint>

#define N_NODES 118784
#define N_EDGES 1900544
#define NROI 116
#define HID 64
#define D1 3712
#define BATCH 1024
#define KDIM 7424   // N_ROI * HIDDEN

// sort geometry: 232 blocks x 8192 edges == N_EDGES ; 464 buckets x 256 nodes == N_NODES
#define EPB 8192
#define NBLK 232
#define BUCKETS 464

typedef __attribute__((ext_vector_type(8))) short s16x8;
typedef __attribute__((ext_vector_type(4))) float f32x4;

__device__ __forceinline__ float mishf(float x) {
    if (x > 20.f) return x;
    float e = __expf(x);
    float n = e * e + 2.f * e;
    return x * n / (n + 2.f);
}
__device__ __forceinline__ float bflo(unsigned u) { return __uint_as_float(u << 16); }
__device__ __forceinline__ float bfhi(unsigned u) { return __uint_as_float(u & 0xFFFF0000u); }

// --- build BT1 [128][256] bf16 (padded [w1_l; w1_r]^T) + bias1p[128] ---------
__global__ void concat1_kernel(const float* __restrict__ w1_l,
                               const float* __restrict__ w1_r,
                               const float* __restrict__ b1,
                               __hip_bfloat16* __restrict__ BT1,
                               float* __restrict__ bias1p) {
    int idx = blockIdx.x * 256 + threadIdx.x;
    if (idx >= 128 * 256) return;
    int j = idx >> 8, k = idx & 255;
    float v = 0.f;
    if (j < NROI) {
        if (k < NROI) v = w1_l[k * NROI + j];
        else if (k < 2 * NROI) v = w1_r[(k - NROI) * NROI + j];
    }
    BT1[idx] = __float2bfloat16(v);
    if (idx < 128) bias1p[idx] = (idx < NROI) ? b1[idx] : 0.f;
}

// --- build BT2 [128][128] bf16 (padded [w2_l | w2_r]^T) ----------------------
__global__ void concat2_kernel(const float* __restrict__ w2_l,
                               const float* __restrict__ w2_r,
                               __hip_bfloat16* __restrict__ BT2) {
    int idx = blockIdx.x * 256 + threadIdx.x;
    if (idx >= 128 * 128) return;
    int j = idx >> 7, k = idx & 127;
    float v = 0.f;
    if (k < NROI) v = (j < HID) ? w2_l[k * HID + j] : w2_r[k * HID + (j - HID)];
    BT2[idx] = __float2bfloat16(v);
}

// --- x fp32 -> xb bf16 (row-major [N][116]) ----------------------------------
__global__ void xconv_kernel(const float* __restrict__ x,
                             __hip_bfloat16* __restrict__ xb) {
    long i = (long)blockIdx.x * 256 + threadIdx.x;   // one thread per 2 elems
    if (i >= (long)N_NODES * 58) return;
    float2 v = *(const float2*)(x + 2 * i);
    __hip_bfloat162 o;
    o.x = __float2bfloat16(v.x);
    o.y = __float2bfloat16(v.y);
    *(__hip_bfloat162*)((__hip_bfloat16*)xb + 2 * i) = o;
}

// =============== deterministic CSR build via 2-level counting sort ===========
// A: per-block bucket histogram -> HT[bucket][block]
__global__ __launch_bounds__(256) void sortA_kernel(const int* __restrict__ dst,
                                                    int* __restrict__ HT) {
    __shared__ int h[BUCKETS];
    int t = threadIdx.x;
    for (int i = t; i < BUCKETS; i += 256) h[i] = 0;
    __syncthreads();
    int base = blockIdx.x * EPB;
    for (int i = t; i < EPB; i += 256) atomicAdd(&h[dst[base + i] >> 8], 1);
    __syncthreads();
    for (int i = t; i < BUCKETS; i += 256) HT[i * NBLK + blockIdx.x] = h[i];
}

// B: single-block exclusive scan of HT (length 464*232), 4 elems/thread
__global__ __launch_bounds__(1024) void sortB_kernel(int* __restrict__ HT) {
    const int L = BUCKETS * NBLK;   // 107648
    __shared__ int sh[1024];
    __shared__ int carry;
    int t = threadIdx.x;
    if (t == 0) carry = 0;
    __syncthreads();
    for (int base = 0; base < L; base += 4096) {
        int i0 = base + 4 * t;
        int4 v = {0, 0, 0, 0};
        if (i0 + 3 < L) v = *(const int4*)(HT + i0);
        else {
            if (i0 < L) v.x = HT[i0];
            if (i0 + 1 < L) v.y = HT[i0 + 1];
            if (i0 + 2 < L) v.z = HT[i0 + 2];
        }
        int s4 = v.x + v.y + v.z + v.w;
        sh[t] = s4;
        __syncthreads();
        for (int d = 1; d < 1024; d <<= 1) {
            int a = (t >= d) ? sh[t - d] : 0;
            __syncthreads();
            sh[t] += a;
            __syncthreads();
        }
        int excl = sh[t] - s4 + carry;
        int4 o;
        o.x = excl; o.y = excl + v.x; o.z = o.y + v.y; o.w = o.z + v.z;
        if (i0 + 3 < L) *(int4*)(HT + i0) = o;
        else {
            if (i0 < L) HT[i0] = o.x;
            if (i0 + 1 < L) HT[i0 + 1] = o.y;
            if (i0 + 2 < L) HT[i0 + 2] = o.z;
        }
        __syncthreads();
        if (t == 1023) carry += sh[1023];
        __syncthreads();
    }
}

// C: scatter (src,dst) pairs into bucket-sorted order (coalesced-ish runs)
__global__ __launch_bounds__(256) void sortC_kernel(const int* __restrict__ src,
                                                    const int* __restrict__ dst,
                                                    const int* __restrict__ HT,
                                                    int2* __restrict__ pairs) {
    __shared__ int cur[BUCKETS];
    int t = threadIdx.x;
    for (int i = t; i < BUCKETS; i += 256) cur[i] = HT[i * NBLK + blockIdx.x];
    __syncthreads();
    int base = blockIdx.x * EPB;
    for (int i = t; i < EPB; i += 256) {
        int d = dst[base + i];
        int s = src[base + i];
        int pos = atomicAdd(&cur[d >> 8], 1);
        pairs[pos] = make_int2(s, d);
    }
}

// D: per-bucket exact CSR (256 nodes/bucket): ssrc + cnt + rowend
__global__ __launch_bounds__(256) void sortD_kernel(const int2* __restrict__ pairs,
                                                    const int* __restrict__ HT,
                                                    int* __restrict__ ssrc,
                                                    int* __restrict__ cnt,
                                                    int* __restrict__ rowend) {
    __shared__ int h[256], sc_[256], cur[256];
    int b = blockIdx.x;
    int t = threadIdx.x;
    int start = HT[b * NBLK];
    int end = (b == BUCKETS - 1) ? N_EDGES : HT[(b + 1) * NBLK];
    h[t] = 0;
    __syncthreads();
    for (int i = start + t; i < end; i += 256) atomicAdd(&h[pairs[i].y & 255], 1);
    __syncthreads();
    int v = h[t];
    sc_[t] = v;
    __syncthreads();
    for (int d = 1; d < 256; d <<= 1) {
        int a = (t >= d) ? sc_[t - d] : 0;
        __syncthreads();
        sc_[t] += a;
        __syncthreads();
    }
    int excl = sc_[t] - v;
    int node = b * 256 + t;
    cnt[node] = v;
    rowend[node] = start + excl + v;
    cur[t] = start + excl;
    __syncthreads();
    for (int i = start + t; i < end; i += 256) {
        int2 p = pairs[i];
        int pos = atomicAdd(&cur[p.y & 255], 1);
        ssrc[pos] = p.x;
    }
}

// --- conv1 gather: 2 neighbors/iter via half-wave, 8B loads ------------------
// Ac1[n] = [ bf16(mean_{j in N(n)} xb[j]) (116) | xb[n] (116) | 0 (24) ]
__global__ __launch_bounds__(256) void gather1_kernel(
    const int* __restrict__ ssrc, const int* __restrict__ rowend,
    const int* __restrict__ cnt, const __hip_bfloat16* __restrict__ xb,
    __hip_bfloat16* __restrict__ Ac1) {
    int node = blockIdx.x * 4 + (threadIdx.x >> 6);
    int lane = threadIdx.x & 63;
    if (node >= N_NODES) return;
    int deg = cnt[node];
    int start = rowend[node] - deg;
    const int half = lane >> 5;
    const int q29 = lane & 31;
    const bool act = q29 < 29;
    const unsigned short* xbs = (const unsigned short*)xb;
    float f0 = 0.f, f1 = 0.f, f2 = 0.f, f3 = 0.f;

#define G1_PAIR(J)                                                              \
    {                                                                           \
        int jj = (J) + half;                                                    \
        int s = __shfl(idx, jj);                                                \
        unsigned long long u = 0ull;                                            \
        if (act && jj < n)                                                      \
            u = *(const unsigned long long*)(xbs + (long)s * NROI + q29 * 4);   \
        unsigned lo = (unsigned)u, hi = (unsigned)(u >> 32);                    \
        f0 += bflo(lo); f1 += bfhi(lo); f2 += bflo(hi); f3 += bfhi(hi);         \
    }

    for (int base = 0; base < deg; base += 64) {
        int n = min(deg - base, 64);
        int idx = (lane < n) ? ssrc[start + base + lane] : 0;
        int j = 0;
        for (; j + 7 < n; j += 8) {
            G1_PAIR(j) G1_PAIR(j + 2) G1_PAIR(j + 4) G1_PAIR(j + 6)
        }
        for (; j < n; j += 2) { G1_PAIR(j) }
    }
#undef G1_PAIR
    f0 += __shfl_xor(f0, 32);
    f1 += __shfl_xor(f1, 32);
    f2 += __shfl_xor(f2, 32);
    f3 += __shfl_xor(f3, 32);

    unsigned short* rowp = (unsigned short*)Ac1 + (long)node * 256;
    if (half == 0 && act) {
        float inv = 1.f / fmaxf((float)deg, 1.f);
        __hip_bfloat162 p0, p1;
        p0.x = __float2bfloat16(f0 * inv);
        p0.y = __float2bfloat16(f1 * inv);
        p1.x = __float2bfloat16(f2 * inv);
        p1.y = __float2bfloat16(f3 * inv);
        unsigned u0 = *(unsigned*)&p0, u1 = *(unsigned*)&p1;
        *(unsigned long long*)(rowp + q29 * 4) =
            (unsigned long long)u0 | ((unsigned long long)u1 << 32);
        // self row straight copy
        *(unsigned long long*)(rowp + NROI + q29 * 4) =
            *(const unsigned long long*)(xbs + (long)node * NROI + q29 * 4);
    }
    if (q29 >= 29) {   // zero-pad shorts 232..255 (6 x 8B from both halves)
        int p6 = (q29 - 29) + 3 * half;
        *(unsigned long long*)(rowp + 2 * NROI + p6 * 4) = 0ull;
    }
}

// --- conv2 gather: 2 neighbors/iter via half-wave, 4B loads ------------------
__global__ __launch_bounds__(256) void gather2_kernel(
    const int* __restrict__ ssrc, const int* __restrict__ rowend,
    const int* __restrict__ cnt, const __hip_bfloat16* __restrict__ q,
    const float* __restrict__ b2, __hip_bfloat16* __restrict__ h2bf) {
    int node = blockIdx.x * 4 + (threadIdx.x >> 6);
    int lane = threadIdx.x & 63;
    if (node >= N_NODES) return;
    int deg = cnt[node];
    int start = rowend[node] - deg;
    const int half = lane >> 5;
    const int fp = lane & 31;          // feature pair: 2fp, 2fp+1
    const unsigned short* qs = (const unsigned short*)q;
    float sx = 0.f, sy = 0.f;

#define G2_PAIR(J)                                                              \
    {                                                                           \
        int jj = (J) + half;                                                    \
        int s = __shfl(idx, jj);                                                \
        unsigned u = 0u;                                                        \
        if (jj < n) u = *(const unsigned*)(qs + (long)s * 128 + fp * 2);        \
        sx += bflo(u); sy += bfhi(u);                                           \
    }

    for (int base = 0; base < deg; base += 64) {
        int n = min(deg - base, 64);
        int idx = (lane < n) ? ssrc[start + base + lane] : 0;
        int j = 0;
        for (; j + 7 < n; j += 8) {
            G2_PAIR(j) G2_PAIR(j + 2) G2_PAIR(j + 4) G2_PAIR(j + 6)
        }
        for (; j < n; j += 2) { G2_PAIR(j) }
    }
#undef G2_PAIR
    sx += __shfl_xor(sx, 32);
    sy += __shfl_xor(sy, 32);

    if (half == 0) {
        float c = fmaxf((float)deg, 1.f);
        unsigned su = *(const unsigned*)(qs + (long)node * 128 + 64 + fp * 2);
        float2 bb = *(const float2*)(b2 + 2 * fp);
        float vx = mishf(sx / c + bflo(su) + bb.x);
        float vy = mishf(sy / c + bfhi(su) + bb.y);
        __hip_bfloat162 o;
        o.x = __float2bfloat16(vx);
        o.y = __float2bfloat16(vy);
        *(unsigned*)((unsigned short*)h2bf + (long)node * 64 + fp * 2) = *(unsigned*)&o;
    }
}

// --- unified conv MFMA GEMM: C[M][128] = act(A[M][Kpad] @ BT^T + bias) -------
__global__ __launch_bounds__(256) void conv_mfma_kernel(
    const __hip_bfloat16* __restrict__ Abf, int Kpad,
    const __hip_bfloat16* __restrict__ BT,
    const float* __restrict__ bias,
    __hip_bfloat16* __restrict__ C, int act) {
    __shared__ short As[128][40];
    __shared__ short Bs[128][40];
    const int t = threadIdx.x;
    const long row0 = (long)blockIdx.x * 128;

    const int sr = t >> 2;
    const int sc = (t & 3) << 3;
    const short* Ap = (const short*)Abf + (row0 + sr) * Kpad + sc;
    const short* Bp = (const short*)BT + sr * Kpad + sc;

    s16x8 ra0 = *(const s16x8*)(Ap);
    s16x8 ra1 = *(const s16x8*)(Ap + 64 * (long)Kpad);
    s16x8 rb0 = *(const s16x8*)(Bp);
    s16x8 rb1 = *(const s16x8*)(Bp + 64 * Kpad);

    const int lane = t & 63;
    const int wid = t >> 6;
    const int wr = (wid >> 1) << 6;
    const int wc = (wid & 1) << 6;
    const int fm = lane & 15;
    const int fk = (lane >> 4) << 3;

    f32x4 acc[4][4];
#pragma unroll
    for (int i = 0; i < 4; i++)
#pragma unroll
        for (int j = 0; j < 4; j++) acc[i][j] = (f32x4){0.f, 0.f, 0.f, 0.f};

    for (int k0 = 0; k0 < Kpad; k0 += 32) {
        *(s16x8*)&As[sr][sc] = ra0;
        *(s16x8*)&As[sr + 64][sc] = ra1;
        *(s16x8*)&Bs[sr][sc] = rb0;
        *(s16x8*)&Bs[sr + 64][sc] = rb1;
        __syncthreads();
        if (k0 + 32 < Kpad) {
            ra0 = *(const s16x8*)(Ap + k0 + 32);
            ra1 = *(const s16x8*)(Ap + 64 * (long)Kpad + k0 + 32);
            rb0 = *(const s16x8*)(Bp + k0 + 32);
            rb1 = *(const s16x8*)(Bp + 64 * Kpad + k0 + 32);
        }
        s16x8 a[4], b[4];
#pragma unroll
        for (int i = 0; i < 4; i++) a[i] = *(const s16x8*)&As[wr + i * 16 + fm][fk];
#pragma unroll
        for (int j = 0; j < 4; j++) b[j] = *(const s16x8*)&Bs[wc + j * 16 + fm][fk];
#pragma unroll
        for (int i = 0; i < 4; i++)
#pragma unroll
            for (int j = 0; j < 4; j++)
                acc[i][j] = __builtin_amdgcn_mfma_f32_16x16x32_bf16(
                    a[i], b[j], acc[i][j], 0, 0, 0);
        __syncthreads();
    }

#pragma unroll
    for (int i = 0; i < 4; i++) {
#pragma unroll
        for (int j = 0; j < 4; j++) {
            int gc = wc + j * 16 + fm;
            float bv = bias ? bias[gc] : 0.f;
#pragma unroll
            for (int r = 0; r < 4; r++) {
                long gr = row0 + wr + i * 16 + ((lane >> 4) << 2) + r;
                float v = acc[i][j][r] + bv;
                if (act) v = mishf(v);
                C[gr * 128 + gc] = __float2bfloat16(v);
            }
        }
    }
}

// --- tiled transpose + fp32->bf16: W[7424][3712] -> WT[3712][7424] -----------
__global__ __launch_bounds__(256) void transpose_bf16_kernel(
    const float* __restrict__ W, __hip_bfloat16* __restrict__ WT) {
    __shared__ float tile[32][33];
    const int t = threadIdx.x;
    const int tn = t & 31, tk = t >> 5;
    const int n0 = blockIdx.x * 32;
    const int k0 = blockIdx.y * 32;
#pragma unroll
    for (int i = 0; i < 4; i++) {
        tile[tk + i * 8][tn] = W[(long)(k0 + tk + i * 8) * D1 + (n0 + tn)];
    }
    __syncthreads();
#pragma unroll
    for (int i = 0; i < 4; i++) {
        int n = n0 + tk + i * 8;
        int k = k0 + tn;
        WT[(long)n * KDIM + k] = __float2bfloat16(tile[tn][tk + i * 8]);
    }
}

// --- lin1 via bf16 MFMA: 64x128 tiles, 464 blocks, XCD col-grouped -----------
// id -> xcd = id&7; col = (id&7) + 8*(id>>7); row = (id>>3)&15.
// All 16 row-blocks of a col stripe share id%8 -> same XCD L2 for the B stripe.
__global__ __launch_bounds__(256) void lin1_mfma_kernel(
    const __hip_bfloat16* __restrict__ Abf,
    const __hip_bfloat16* __restrict__ BTbf,
    const float* __restrict__ bias,
    float* __restrict__ C) {
    __shared__ short As[64][40];
    __shared__ short Bs[128][40];
    const int t = threadIdx.x;
    const int id = blockIdx.x;
    const int xx = id & 7;
    const int r = (id >> 3) & 15;
    const int cg = id >> 7;
    const int c = xx + 8 * cg;
    if (c >= D1 / 128) return;     // 29 col stripes; 48 dead blocks of 512
    const long row0 = (long)r * 64;
    const long col0 = (long)c * 128;

    const int sr = t >> 2;          // 0..63
    const int sc = (t & 3) << 3;
    const short* Ap = (const short*)Abf + (row0 + sr) * KDIM + sc;
    const short* Bp = (const short*)BTbf + (col0 + sr) * KDIM + sc;

    s16x8 ra0 = *(const s16x8*)(Ap);
    s16x8 rb0 = *(const s16x8*)(Bp);
    s16x8 rb1 = *(const s16x8*)(Bp + 64 * KDIM);

    const int lane = t & 63;
    const int wid = t >> 6;
    const int wr = (wid >> 1) << 5;   // 0 / 32
    const int wc = (wid & 1) << 6;    // 0 / 64
    const int fm = lane & 15;
    const int fk = (lane >> 4) << 3;

    f32x4 acc[2][4];
#pragma unroll
    for (int i = 0; i < 2; i++)
#pragma unroll
        for (int j = 0; j < 4; j++) acc[i][j] = (f32x4){0.f, 0.f, 0.f, 0.f};

    for (int k0 = 0; k0 < KDIM; k0 += 32) {
        *(s16x8*)&As[sr][sc] = ra0;
        *(s16x8*)&Bs[sr][sc] = rb0;
        *(s16x8*)&Bs[sr + 64][sc] = rb1;
        __syncthreads();
        if (k0 + 32 < KDIM) {
            ra0 = *(const s16x8*)(Ap + k0 + 32);
            rb0 = *(const s16x8*)(Bp + k0 + 32);
            rb1 = *(const s16x8*)(Bp + 64 * KDIM + k0 + 32);
        }
        s16x8 a[2], b[4];
#pragma unroll
        for (int i = 0; i < 2; i++) a[i] = *(const s16x8*)&As[wr + i * 16 + fm][fk];
#pragma unroll
        for (int j = 0; j < 4; j++) b[j] = *(const s16x8*)&Bs[wc + j * 16 + fm][fk];
#pragma unroll
        for (int i = 0; i < 2; i++)
#pragma unroll
            for (int j = 0; j < 4; j++)
                acc[i][j] = __builtin_amdgcn_mfma_f32_16x16x32_bf16(
                    a[i], b[j], acc[i][j], 0, 0, 0);
        __syncthreads();
    }

#pragma unroll
    for (int i = 0; i < 2; i++) {
#pragma unroll
        for (int j = 0; j < 4; j++) {
            int gc = (int)col0 + wc + j * 16 + fm;
            float bv = bias[gc];
#pragma unroll
            for (int rr = 0; rr < 4; rr++) {
                long gr = row0 + wr + i * 16 + ((lane >> 4) << 2) + rr;
                C[gr * D1 + gc] = acc[i][j][rr] + bv;
            }
        }
    }
}

// --- fused layernorm + mish + lin2 tail --------------------------------------
__global__ __launch_bounds__(256) void tail_kernel(
    const float* __restrict__ t1, const float* __restrict__ g,
    const float* __restrict__ b, const float* __restrict__ w2,
    const float* __restrict__ b2, float* __restrict__ out) {
    int row = blockIdx.x;
    const float* h = t1 + (long)row * D1;
    int t = threadIdx.x;
    int w = t >> 6, lane = t & 63;
    float s = 0.f, ss = 0.f;
    for (int i = t; i < D1; i += 256) {
        float v = h[i];
        s += v;
        ss += v * v;
    }
    for (int d = 32; d > 0; d >>= 1) {
        s += __shfl_down(s, d);
        ss += __shfl_down(ss, d);
    }
    __shared__ float sh[8];
    if (lane == 0) { sh[w] = s; sh[4 + w] = ss; }
    __syncthreads();
    if (t == 0) {
        sh[0] = sh[0] + sh[1] + sh[2] + sh[3];
        sh[4] = sh[4] + sh[5] + sh[6] + sh[7];
    }
    __syncthreads();
    float mu = sh[0] * (1.f / D1);
    float var = sh[4] * (1.f / D1) - mu * mu;
    float rs = rsqrtf(var + 1e-5f);
    float d0 = 0.f, d1 = 0.f;
    for (int i = t; i < D1; i += 256) {
        float v = (h[i] - mu) * rs * g[i] + b[i];
        v = mishf(v);
        d0 += v * w2[2 * i];
        d1 += v * w2[2 * i + 1];
    }
    for (int d = 32; d > 0; d >>= 1) {
        d0 += __shfl_down(d0, d);
        d1 += __shfl_down(d1, d);
    }
    __shared__ float sh2[8];
    if (lane == 0) { sh2[w] = d0; sh2[4 + w] = d1; }
    __syncthreads();
    if (t == 0) {
        out[2 * row] = sh2[0] + sh2[1] + sh2[2] + sh2[3] + b2[0];
        out[2 * row + 1] = sh2[4] + sh2[5] + sh2[6] + sh2[7] + b2[1];
    }
}

extern "C" void kernel_launch(void* const* d_in, const int* in_sizes, int n_in,
                              void* d_out, int out_size, void* d_ws, size_t ws_size,
                              hipStream_t stream) {
    const float* x      = (const float*)d_in[0];
    const int*   ei     = (const int*)d_in[1];
    const float* w1_l   = (const float*)d_in[2];
    const float* b1     = (const float*)d_in[3];
    const float* w1_r   = (const float*)d_in[4];
    const float* w2_l   = (const float*)d_in[5];
    const float* b2     = (const float*)d_in[6];
    const float* w2_r   = (const float*)d_in[7];
    const float* w_lin1 = (const float*)d_in[8];
    const float* b_lin1 = (const float*)d_in[9];
    const float* ln_g   = (const float*)d_in[10];
    const float* ln_b   = (const float*)d_in[11];
    const float* w_lin2 = (const float*)d_in[12];
    const float* b_lin2 = (const float*)d_in[13];
    float* out = (float*)d_out;

    char* ws = (char*)d_ws;
    // workspace layout (bytes), liveness-based reuse (max ~161.2MB, <171.7 proven):
    //   [0,          60,817,408)  Ac1 bf16 [N][256] (gather1->conv1)
    //                             -> wT bf16 [3712][7424] (transpose->lin1)
    //   [60,817,408, 91,226,112)  h1b bf16 [N][128] (conv1->conv2)
    //   [91,226,112, 121,634,816) xb bf16 (xconv->gather1) -> q bf16 (conv2->gather2)
    //   [121,634,816,136,839,168) pairs int2[E] (sortC->sortD) -> t1 fp32 (lin1->tail)
    //   [136,839,168,137,314,304) cnt int[N]
    //   [137,314,304,137,789,440) rowend int[N]
    //   [137,789,440,138,220,032) HT int[464*232]
    //   [138,220,032,145,822,208) ssrc int[E]
    //   [145,822,208,161,026,560) h2bf bf16 [N][64] (gather2->lin1)
    //   [161,026,560,161,092,096) BT1 ; [..]+512 bias1p ; +32K BT2
    __hip_bfloat16* Ac1   = (__hip_bfloat16*)(ws + 0);
    __hip_bfloat16* wT    = (__hip_bfloat16*)(ws + 0);
    __hip_bfloat16* h1b   = (__hip_bfloat16*)(ws + 60817408);
    __hip_bfloat16* xb    = (__hip_bfloat16*)(ws + 91226112);
    __hip_bfloat16* q     = (__hip_bfloat16*)(ws + 91226112);
    int2*  pairs          = (int2*)(ws + 121634816);
    float* t1             = (float*)(ws + 121634816);
    int*   cnt            = (int*)(ws + 136839168);
    int*   rowend         = (int*)(ws + 137314304);
    int*   HT             = (int*)(ws + 137789440);
    int*   ssrc           = (int*)(ws + 138220032);
    __hip_bfloat16* h2bf  = (__hip_bfloat16*)(ws + 145822208);
    __hip_bfloat16* BT1   = (__hip_bfloat16*)(ws + 161026560);
    float* bias1p         = (float*)(ws + 161092096);
    __hip_bfloat16* BT2   = (__hip_bfloat16*)(ws + 161092608);

    const int* src = ei;
    const int* dst = ei + N_EDGES;

    // --- CSR build: deterministic 2-level counting sort ---
    sortA_kernel<<<NBLK, 256, 0, stream>>>(dst, HT);
    sortB_kernel<<<1, 1024, 0, stream>>>(HT);
    sortC_kernel<<<NBLK, 256, 0, stream>>>(src, dst, HT, pairs);
    sortD_kernel<<<BUCKETS, 256, 0, stream>>>(pairs, HT, ssrc, cnt, rowend);

    // --- padded bf16 weights + bf16 x ---
    concat1_kernel<<<(128 * 256 + 255) / 256, 256, 0, stream>>>(w1_l, w1_r, b1, BT1, bias1p);
    concat2_kernel<<<(128 * 128 + 255) / 256, 256, 0, stream>>>(w2_l, w2_r, BT2);
    xconv_kernel<<<(int)(((long)N_NODES * 58 + 255) / 256), 256, 0, stream>>>(x, xb);

    // --- conv1: gather-mean (bf16 in, packed bf16 A out) then MFMA GEMM ---
    gather1_kernel<<<(N_NODES + 3) / 4, 256, 0, stream>>>(ssrc, rowend, cnt, xb, Ac1);
    conv_mfma_kernel<<<N_NODES / 128, 256, 0, stream>>>(Ac1, 256, BT1, bias1p, h1b, 1);

    // --- conv2: project first (q = h1 @ [w2_l|w2_r]), gather, combine ---
    conv_mfma_kernel<<<N_NODES / 128, 256, 0, stream>>>(h1b, 128, BT2, nullptr, q, 0);
    gather2_kernel<<<(N_NODES + 3) / 4, 256, 0, stream>>>(ssrc, rowend, cnt, q, b2, h2bf);

    // --- lin1 (bf16 MFMA, 64x128 tiles, XCD col-grouped); wT overlaps dead Ac1 ---
    transpose_bf16_kernel<<<dim3(D1 / 32, KDIM / 32), 256, 0, stream>>>(w_lin1, wT);
    lin1_mfma_kernel<<<512, 256, 0, stream>>>(h2bf, wT, b_lin1, t1);

    // --- layernorm + mish + lin2 ---
    tail_kernel<<<BATCH, 256, 0, stream>>>(t1, ln_g, ln_b, w_lin2, b_lin2, out);
}

// Round 7
// 663.821 us; speedup vs baseline: 4.7303x; 1.0121x over previous
//
#include <hip/hip_runtime.h>
#include <hip/hip_bf16.h>
#include <cstdint>

#define N_NODES 118784
#define N_EDGES 1900544
#define NROI 116
#define HID 64
#define D1 3712
#define BATCH 1024
#define KDIM 7424   // N_ROI * HIDDEN

// sort geometry: 232 blocks x 8192 edges == N_EDGES ; 464 buckets x 256 nodes == N_NODES
#define EPB 8192
#define NBLK 232
#define BUCKETS 464

typedef __attribute__((ext_vector_type(8))) short s16x8;
typedef __attribute__((ext_vector_type(4))) float f32x4;

__device__ __forceinline__ float mishf(float x) {
    if (x > 20.f) return x;
    float e = __expf(x);
    float n = e * e + 2.f * e;
    return x * n / (n + 2.f);
}
__device__ __forceinline__ float bflo(unsigned u) { return __uint_as_float(u << 16); }
__device__ __forceinline__ float bfhi(unsigned u) { return __uint_as_float(u & 0xFFFF0000u); }

// --- build BT1 [128][256] bf16 (padded [w1_l; w1_r]^T) + bias1p[128] ---------
__global__ void concat1_kernel(const float* __restrict__ w1_l,
                               const float* __restrict__ w1_r,
                               const float* __restrict__ b1,
                               __hip_bfloat16* __restrict__ BT1,
                               float* __restrict__ bias1p) {
    int idx = blockIdx.x * 256 + threadIdx.x;
    if (idx >= 128 * 256) return;
    int j = idx >> 8, k = idx & 255;
    float v = 0.f;
    if (j < NROI) {
        if (k < NROI) v = w1_l[k * NROI + j];
        else if (k < 2 * NROI) v = w1_r[(k - NROI) * NROI + j];
    }
    BT1[idx] = __float2bfloat16(v);
    if (idx < 128) bias1p[idx] = (idx < NROI) ? b1[idx] : 0.f;
}

// --- build BT2 [128][128] bf16 (padded [w2_l | w2_r]^T) ----------------------
__global__ void concat2_kernel(const float* __restrict__ w2_l,
                               const float* __restrict__ w2_r,
                               __hip_bfloat16* __restrict__ BT2) {
    int idx = blockIdx.x * 256 + threadIdx.x;
    if (idx >= 128 * 128) return;
    int j = idx >> 7, k = idx & 127;
    float v = 0.f;
    if (k < NROI) v = (j < HID) ? w2_l[k * HID + j] : w2_r[k * HID + (j - HID)];
    BT2[idx] = __float2bfloat16(v);
}

// --- x fp32 -> xb bf16 (row-major [N][116]) ----------------------------------
__global__ void xconv_kernel(const float* __restrict__ x,
                             __hip_bfloat16* __restrict__ xb) {
    long i = (long)blockIdx.x * 256 + threadIdx.x;   // one thread per 2 elems
    if (i >= (long)N_NODES * 58) return;
    float2 v = *(const float2*)(x + 2 * i);
    __hip_bfloat162 o;
    o.x = __float2bfloat16(v.x);
    o.y = __float2bfloat16(v.y);
    *(__hip_bfloat162*)((__hip_bfloat16*)xb + 2 * i) = o;
}

// =============== deterministic CSR build via 2-level counting sort ===========
__global__ __launch_bounds__(256) void sortA_kernel(const int* __restrict__ dst,
                                                    int* __restrict__ HT) {
    __shared__ int h[BUCKETS];
    int t = threadIdx.x;
    for (int i = t; i < BUCKETS; i += 256) h[i] = 0;
    __syncthreads();
    int base = blockIdx.x * EPB;
    for (int i = t; i < EPB; i += 256) atomicAdd(&h[dst[base + i] >> 8], 1);
    __syncthreads();
    for (int i = t; i < BUCKETS; i += 256) HT[i * NBLK + blockIdx.x] = h[i];
}

__global__ __launch_bounds__(1024) void sortB_kernel(int* __restrict__ HT) {
    const int L = BUCKETS * NBLK;   // 107648
    __shared__ int sh[1024];
    __shared__ int carry;
    int t = threadIdx.x;
    if (t == 0) carry = 0;
    __syncthreads();
    for (int base = 0; base < L; base += 4096) {
        int i0 = base + 4 * t;
        int4 v = {0, 0, 0, 0};
        if (i0 + 3 < L) v = *(const int4*)(HT + i0);
        else {
            if (i0 < L) v.x = HT[i0];
            if (i0 + 1 < L) v.y = HT[i0 + 1];
            if (i0 + 2 < L) v.z = HT[i0 + 2];
        }
        int s4 = v.x + v.y + v.z + v.w;
        sh[t] = s4;
        __syncthreads();
        for (int d = 1; d < 1024; d <<= 1) {
            int a = (t >= d) ? sh[t - d] : 0;
            __syncthreads();
            sh[t] += a;
            __syncthreads();
        }
        int excl = sh[t] - s4 + carry;
        int4 o;
        o.x = excl; o.y = excl + v.x; o.z = o.y + v.y; o.w = o.z + v.z;
        if (i0 + 3 < L) *(int4*)(HT + i0) = o;
        else {
            if (i0 < L) HT[i0] = o.x;
            if (i0 + 1 < L) HT[i0 + 1] = o.y;
            if (i0 + 2 < L) HT[i0 + 2] = o.z;
        }
        __syncthreads();
        if (t == 1023) carry += sh[1023];
        __syncthreads();
    }
}

__global__ __launch_bounds__(256) void sortC_kernel(const int* __restrict__ src,
                                                    const int* __restrict__ dst,
                                                    const int* __restrict__ HT,
                                                    int2* __restrict__ pairs) {
    __shared__ int cur[BUCKETS];
    int t = threadIdx.x;
    for (int i = t; i < BUCKETS; i += 256) cur[i] = HT[i * NBLK + blockIdx.x];
    __syncthreads();
    int base = blockIdx.x * EPB;
    for (int i = t; i < EPB; i += 256) {
        int d = dst[base + i];
        int s = src[base + i];
        int pos = atomicAdd(&cur[d >> 8], 1);
        pairs[pos] = make_int2(s, d);
    }
}

__global__ __launch_bounds__(256) void sortD_kernel(const int2* __restrict__ pairs,
                                                    const int* __restrict__ HT,
                                                    int* __restrict__ ssrc,
                                                    int* __restrict__ cnt,
                                                    int* __restrict__ rowend) {
    __shared__ int h[256], sc_[256], cur[256];
    int b = blockIdx.x;
    int t = threadIdx.x;
    int start = HT[b * NBLK];
    int end = (b == BUCKETS - 1) ? N_EDGES : HT[(b + 1) * NBLK];
    h[t] = 0;
    __syncthreads();
    for (int i = start + t; i < end; i += 256) atomicAdd(&h[pairs[i].y & 255], 1);
    __syncthreads();
    int v = h[t];
    sc_[t] = v;
    __syncthreads();
    for (int d = 1; d < 256; d <<= 1) {
        int a = (t >= d) ? sc_[t - d] : 0;
        __syncthreads();
        sc_[t] += a;
        __syncthreads();
    }
    int excl = sc_[t] - v;
    int node = b * 256 + t;
    cnt[node] = v;
    rowend[node] = start + excl + v;
    cur[t] = start + excl;
    __syncthreads();
    for (int i = start + t; i < end; i += 256) {
        int2 p = pairs[i];
        int pos = atomicAdd(&cur[p.y & 255], 1);
        ssrc[pos] = p.x;
    }
}

// --- conv1 gather: 4 neighbors/instr via quarter-wave, 16B loads -------------
// Ac1[n] = [ bf16(mean_{j in N(n)} xb[j]) (116) | xb[n] (116) | 0 (24) ]
__global__ __launch_bounds__(256) void gather1_kernel(
    const int* __restrict__ ssrc, const int* __restrict__ rowend,
    const int* __restrict__ cnt, const __hip_bfloat16* __restrict__ xb,
    __hip_bfloat16* __restrict__ Ac1) {
    int node = blockIdx.x * 4 + (threadIdx.x >> 6);
    int lane = threadIdx.x & 63;
    if (node >= N_NODES) return;
    int deg = cnt[node];
    int start = rowend[node] - deg;
    const int qw = lane >> 4;   // quarter: which of 4 in-flight neighbors
    const int l  = lane & 15;   // 16B chunk (0..14 valid; l=14 half-masked)
    const unsigned short* xbs = (const unsigned short*)xb;
    float f0 = 0.f, f1 = 0.f, f2 = 0.f, f3 = 0.f;
    float f4 = 0.f, f5 = 0.f, f6 = 0.f, f7 = 0.f;

#define G1Q(J)                                                                  \
    {                                                                           \
        int jj = (J) + qw;                                                      \
        int s = __shfl(idx, jj);                                                \
        ulonglong2 u = {0ull, 0ull};                                            \
        if (l < 15 && jj < n)                                                   \
            u = *(const ulonglong2*)(xbs + (long)s * NROI + l * 8);             \
        if (l == 14) u.y = 0ull;                                                \
        unsigned a0 = (unsigned)u.x, a1 = (unsigned)(u.x >> 32);                \
        unsigned a2 = (unsigned)u.y, a3 = (unsigned)(u.y >> 32);                \
        f0 += bflo(a0); f1 += bfhi(a0); f2 += bflo(a1); f3 += bfhi(a1);         \
        f4 += bflo(a2); f5 += bfhi(a2); f6 += bflo(a3); f7 += bfhi(a3);         \
    }

    for (int base = 0; base < deg; base += 64) {
        int n = min(deg - base, 64);
        int idx = (lane < n) ? ssrc[start + base + lane] : 0;
        for (int j = 0; j < n; j += 16) {
            G1Q(j) G1Q(j + 4) G1Q(j + 8) G1Q(j + 12)
        }
    }
#undef G1Q
    // combine the 4 quarters: every lane in {l, l+16, l+32, l+48} gets the sum
    f0 += __shfl_xor(f0, 16); f0 += __shfl_xor(f0, 32);
    f1 += __shfl_xor(f1, 16); f1 += __shfl_xor(f1, 32);
    f2 += __shfl_xor(f2, 16); f2 += __shfl_xor(f2, 32);
    f3 += __shfl_xor(f3, 16); f3 += __shfl_xor(f3, 32);
    f4 += __shfl_xor(f4, 16); f4 += __shfl_xor(f4, 32);
    f5 += __shfl_xor(f5, 16); f5 += __shfl_xor(f5, 32);
    f6 += __shfl_xor(f6, 16); f6 += __shfl_xor(f6, 32);
    f7 += __shfl_xor(f7, 16); f7 += __shfl_xor(f7, 32);

    unsigned short* rowp = (unsigned short*)Ac1 + (long)node * 256;
    if (lane < 15) {                 // mean chunks
        float inv = 1.f / fmaxf((float)deg, 1.f);
        __hip_bfloat162 p0, p1, p2, p3;
        p0.x = __float2bfloat16(f0 * inv); p0.y = __float2bfloat16(f1 * inv);
        p1.x = __float2bfloat16(f2 * inv); p1.y = __float2bfloat16(f3 * inv);
        p2.x = __float2bfloat16(f4 * inv); p2.y = __float2bfloat16(f5 * inv);
        p3.x = __float2bfloat16(f6 * inv); p3.y = __float2bfloat16(f7 * inv);
        unsigned u0 = *(unsigned*)&p0, u1 = *(unsigned*)&p1;
        unsigned u2 = *(unsigned*)&p2, u3 = *(unsigned*)&p3;
        unsigned long long w0 = (unsigned long long)u0 | ((unsigned long long)u1 << 32);
        unsigned long long w1 = (unsigned long long)u2 | ((unsigned long long)u3 << 32);
        if (lane < 14) {
            ulonglong2 o = {w0, w1};
            *(ulonglong2*)(rowp + lane * 8) = o;
        } else {
            *(unsigned long long*)(rowp + 112) = w0;   // feats 112..115
        }
    } else if (lane >= 16 && lane < 45) {   // self-row copy, 29 x 8B
        int sl = lane - 16;
        *(unsigned long long*)(rowp + NROI + 4 * sl) =
            *(const unsigned long long*)(xbs + (long)node * NROI + 4 * sl);
    } else if (lane >= 45 && lane < 51) {   // zero pad, 6 x 8B
        int zl = lane - 45;
        *(unsigned long long*)(rowp + 2 * NROI + 4 * zl) = 0ull;
    }
}

// --- conv2 gather: 4 neighbors/instr via quarter-wave, 8B loads --------------
__global__ __launch_bounds__(256) void gather2_kernel(
    const int* __restrict__ ssrc, const int* __restrict__ rowend,
    const int* __restrict__ cnt, const __hip_bfloat16* __restrict__ q,
    const float* __restrict__ b2, __hip_bfloat16* __restrict__ h2bf) {
    int node = blockIdx.x * 4 + (threadIdx.x >> 6);
    int lane = threadIdx.x & 63;
    if (node >= N_NODES) return;
    int deg = cnt[node];
    int start = rowend[node] - deg;
    const int qw = lane >> 4;
    const int l  = lane & 15;      // features 4l..4l+3
    const unsigned short* qs = (const unsigned short*)q;
    float g0 = 0.f, g1 = 0.f, g2 = 0.f, g3 = 0.f;

#define G2Q(J)                                                                  \
    {                                                                           \
        int jj = (J) + qw;                                                      \
        int s = __shfl(idx, jj);                                                \
        unsigned long long u = 0ull;                                            \
        if (jj < n) u = *(const unsigned long long*)(qs + (long)s * 128 + l * 4); \
        unsigned a0 = (unsigned)u, a1 = (unsigned)(u >> 32);                    \
        g0 += bflo(a0); g1 += bfhi(a0); g2 += bflo(a1); g3 += bfhi(a1);         \
    }

    for (int base = 0; base < deg; base += 64) {
        int n = min(deg - base, 64);
        int idx = (lane < n) ? ssrc[start + base + lane] : 0;
        for (int j = 0; j < n; j += 16) {
            G2Q(j) G2Q(j + 4) G2Q(j + 8) G2Q(j + 12)
        }
    }
#undef G2Q
    g0 += __shfl_xor(g0, 16); g0 += __shfl_xor(g0, 32);
    g1 += __shfl_xor(g1, 16); g1 += __shfl_xor(g1, 32);
    g2 += __shfl_xor(g2, 16); g2 += __shfl_xor(g2, 32);
    g3 += __shfl_xor(g3, 16); g3 += __shfl_xor(g3, 32);

    if (lane < 16) {
        float c = fmaxf((float)deg, 1.f);
        unsigned long long su = *(const unsigned long long*)(qs + (long)node * 128 + 64 + l * 4);
        unsigned s0 = (unsigned)su, s1 = (unsigned)(su >> 32);
        float4 bb = *(const float4*)(b2 + 4 * l);
        __hip_bfloat162 o0, o1;
        o0.x = __float2bfloat16(mishf(g0 / c + bflo(s0) + bb.x));
        o0.y = __float2bfloat16(mishf(g1 / c + bfhi(s0) + bb.y));
        o1.x = __float2bfloat16(mishf(g2 / c + bflo(s1) + bb.z));
        o1.y = __float2bfloat16(mishf(g3 / c + bfhi(s1) + bb.w));
        unsigned u0 = *(unsigned*)&o0, u1 = *(unsigned*)&o1;
        *(unsigned long long*)((unsigned short*)h2bf + (long)node * 64 + 4 * l) =
            (unsigned long long)u0 | ((unsigned long long)u1 << 32);
    }
}

// --- unified conv MFMA GEMM: C[M][128] = act(A[M][Kpad] @ BT^T + bias) -------
__global__ __launch_bounds__(256) void conv_mfma_kernel(
    const __hip_bfloat16* __restrict__ Abf, int Kpad,
    const __hip_bfloat16* __restrict__ BT,
    const float* __restrict__ bias,
    __hip_bfloat16* __restrict__ C, int act) {
    __shared__ short As[128][40];
    __shared__ short Bs[128][40];
    const int t = threadIdx.x;
    const long row0 = (long)blockIdx.x * 128;

    const int sr = t >> 2;
    const int sc = (t & 3) << 3;
    const short* Ap = (const short*)Abf + (row0 + sr) * Kpad + sc;
    const short* Bp = (const short*)BT + sr * Kpad + sc;

    s16x8 ra0 = *(const s16x8*)(Ap);
    s16x8 ra1 = *(const s16x8*)(Ap + 64 * (long)Kpad);
    s16x8 rb0 = *(const s16x8*)(Bp);
    s16x8 rb1 = *(const s16x8*)(Bp + 64 * Kpad);

    const int lane = t & 63;
    const int wid = t >> 6;
    const int wr = (wid >> 1) << 6;
    const int wc = (wid & 1) << 6;
    const int fm = lane & 15;
    const int fk = (lane >> 4) << 3;

    f32x4 acc[4][4];
#pragma unroll
    for (int i = 0; i < 4; i++)
#pragma unroll
        for (int j = 0; j < 4; j++) acc[i][j] = (f32x4){0.f, 0.f, 0.f, 0.f};

    for (int k0 = 0; k0 < Kpad; k0 += 32) {
        *(s16x8*)&As[sr][sc] = ra0;
        *(s16x8*)&As[sr + 64][sc] = ra1;
        *(s16x8*)&Bs[sr][sc] = rb0;
        *(s16x8*)&Bs[sr + 64][sc] = rb1;
        __syncthreads();
        if (k0 + 32 < Kpad) {
            ra0 = *(const s16x8*)(Ap + k0 + 32);
            ra1 = *(const s16x8*)(Ap + 64 * (long)Kpad + k0 + 32);
            rb0 = *(const s16x8*)(Bp + k0 + 32);
            rb1 = *(const s16x8*)(Bp + 64 * Kpad + k0 + 32);
        }
        s16x8 a[4], b[4];
#pragma unroll
        for (int i = 0; i < 4; i++) a[i] = *(const s16x8*)&As[wr + i * 16 + fm][fk];
#pragma unroll
        for (int j = 0; j < 4; j++) b[j] = *(const s16x8*)&Bs[wc + j * 16 + fm][fk];
#pragma unroll
        for (int i = 0; i < 4; i++)
#pragma unroll
            for (int j = 0; j < 4; j++)
                acc[i][j] = __builtin_amdgcn_mfma_f32_16x16x32_bf16(
                    a[i], b[j], acc[i][j], 0, 0, 0);
        __syncthreads();
    }

#pragma unroll
    for (int i = 0; i < 4; i++) {
#pragma unroll
        for (int j = 0; j < 4; j++) {
            int gc = wc + j * 16 + fm;
            float bv = bias ? bias[gc] : 0.f;
#pragma unroll
            for (int r = 0; r < 4; r++) {
                long gr = row0 + wr + i * 16 + ((lane >> 4) << 2) + r;
                float v = acc[i][j][r] + bv;
                if (act) v = mishf(v);
                C[gr * 128 + gc] = __float2bfloat16(v);
            }
        }
    }
}

// --- tiled transpose + fp32->bf16: W[7424][3712] -> WT[3712][7424] -----------
__global__ __launch_bounds__(256) void transpose_bf16_kernel(
    const float* __restrict__ W, __hip_bfloat16* __restrict__ WT) {
    __shared__ float tile[32][33];
    const int t = threadIdx.x;
    const int tn = t & 31, tk = t >> 5;
    const int n0 = blockIdx.x * 32;
    const int k0 = blockIdx.y * 32;
#pragma unroll
    for (int i = 0; i < 4; i++) {
        tile[tk + i * 8][tn] = W[(long)(k0 + tk + i * 8) * D1 + (n0 + tn)];
    }
    __syncthreads();
#pragma unroll
    for (int i = 0; i < 4; i++) {
        int n = n0 + tk + i * 8;
        int k = k0 + tn;
        WT[(long)n * KDIM + k] = __float2bfloat16(tile[tn][tk + i * 8]);
    }
}

// --- lin1 via bf16 MFMA: 64x128 tiles, split-K x2, XCD col-grouped -----------
// Grid 1024: xx=id&7 (XCD); r=(id>>3)&15; ks=(id>>7)&1; col=xx+8*(id>>8).
// Partials (no bias) go to C0/C1; tail sums them + bias.
__global__ __launch_bounds__(256) void lin1_mfma_kernel(
    const __hip_bfloat16* __restrict__ Abf,
    const __hip_bfloat16* __restrict__ BTbf,
    float* __restrict__ C0, float* __restrict__ C1) {
    __shared__ short As[64][40];
    __shared__ short Bs[128][40];
    const int t = threadIdx.x;
    const int id = blockIdx.x;
    const int xx = id & 7;
    const int r = (id >> 3) & 15;
    const int ks = (id >> 7) & 1;
    const int c = xx + 8 * (id >> 8);
    if (c >= D1 / 128) return;     // 29 col stripes
    const long row0 = (long)r * 64;
    const long col0 = (long)c * 128;
    const int kbase = ks * (KDIM / 2);
    float* __restrict__ Cp = ks ? C1 : C0;

    const int sr = t >> 2;          // 0..63
    const int sc = (t & 3) << 3;
    const short* Ap = (const short*)Abf + (row0 + sr) * KDIM + kbase + sc;
    const short* Bp = (const short*)BTbf + (col0 + sr) * KDIM + kbase + sc;

    s16x8 ra0 = *(const s16x8*)(Ap);
    s16x8 rb0 = *(const s16x8*)(Bp);
    s16x8 rb1 = *(const s16x8*)(Bp + 64 * KDIM);

    const int lane = t & 63;
    const int wid = t >> 6;
    const int wr = (wid >> 1) << 5;   // 0 / 32
    const int wc = (wid & 1) << 6;    // 0 / 64
    const int fm = lane & 15;
    const int fk = (lane >> 4) << 3;

    f32x4 acc[2][4];
#pragma unroll
    for (int i = 0; i < 2; i++)
#pragma unroll
        for (int j = 0; j < 4; j++) acc[i][j] = (f32x4){0.f, 0.f, 0.f, 0.f};

    for (int k0 = 0; k0 < KDIM / 2; k0 += 32) {
        *(s16x8*)&As[sr][sc] = ra0;
        *(s16x8*)&Bs[sr][sc] = rb0;
        *(s16x8*)&Bs[sr + 64][sc] = rb1;
        __syncthreads();
        if (k0 + 32 < KDIM / 2) {
            ra0 = *(const s16x8*)(Ap + k0 + 32);
            rb0 = *(const s16x8*)(Bp + k0 + 32);
            rb1 = *(const s16x8*)(Bp + 64 * KDIM + k0 + 32);
        }
        s16x8 a[2], b[4];
#pragma unroll
        for (int i = 0; i < 2; i++) a[i] = *(const s16x8*)&As[wr + i * 16 + fm][fk];
#pragma unroll
        for (int j = 0; j < 4; j++) b[j] = *(const s16x8*)&Bs[wc + j * 16 + fm][fk];
#pragma unroll
        for (int i = 0; i < 2; i++)
#pragma unroll
            for (int j = 0; j < 4; j++)
                acc[i][j] = __builtin_amdgcn_mfma_f32_16x16x32_bf16(
                    a[i], b[j], acc[i][j], 0, 0, 0);
        __syncthreads();
    }

#pragma unroll
    for (int i = 0; i < 2; i++) {
#pragma unroll
        for (int j = 0; j < 4; j++) {
            int gc = (int)col0 + wc + j * 16 + fm;
#pragma unroll
            for (int rr = 0; rr < 4; rr++) {
                long gr = row0 + wr + i * 16 + ((lane >> 4) << 2) + rr;
                Cp[gr * D1 + gc] = acc[i][j][rr];
            }
        }
    }
}

// --- fused (t1a+t1b+bias) + layernorm + mish + lin2 tail ---------------------
__global__ __launch_bounds__(256) void tail_kernel(
    const float* __restrict__ t1a, const float* __restrict__ t1b,
    const float* __restrict__ bias,
    const float* __restrict__ g, const float* __restrict__ b,
    const float* __restrict__ w2, const float* __restrict__ b2,
    float* __restrict__ out) {
    int row = blockIdx.x;
    const float* ha = t1a + (long)row * D1;
    const float* hb = t1b + (long)row * D1;
    int t = threadIdx.x;
    int w = t >> 6, lane = t & 63;
    float s = 0.f, ss = 0.f;
    for (int i = t; i < D1; i += 256) {
        float v = ha[i] + hb[i] + bias[i];
        s += v;
        ss += v * v;
    }
    for (int d = 32; d > 0; d >>= 1) {
        s += __shfl_down(s, d);
        ss += __shfl_down(ss, d);
    }
    __shared__ float sh[8];
    if (lane == 0) { sh[w] = s; sh[4 + w] = ss; }
    __syncthreads();
    if (t == 0) {
        sh[0] = sh[0] + sh[1] + sh[2] + sh[3];
        sh[4] = sh[4] + sh[5] + sh[6] + sh[7];
    }
    __syncthreads();
    float mu = sh[0] * (1.f / D1);
    float var = sh[4] * (1.f / D1) - mu * mu;
    float rs = rsqrtf(var + 1e-5f);
    float d0 = 0.f, d1 = 0.f;
    for (int i = t; i < D1; i += 256) {
        float v = ((ha[i] + hb[i] + bias[i]) - mu) * rs * g[i] + b[i];
        v = mishf(v);
        d0 += v * w2[2 * i];
        d1 += v * w2[2 * i + 1];
    }
    for (int d = 32; d > 0; d >>= 1) {
        d0 += __shfl_down(d0, d);
        d1 += __shfl_down(d1, d);
    }
    __shared__ float sh2[8];
    if (lane == 0) { sh2[w] = d0; sh2[4 + w] = d1; }
    __syncthreads();
    if (t == 0) {
        out[2 * row] = sh2[0] + sh2[1] + sh2[2] + sh2[3] + b2[0];
        out[2 * row + 1] = sh2[4] + sh2[5] + sh2[6] + sh2[7] + b2[1];
    }
}

extern "C" void kernel_launch(void* const* d_in, const int* in_sizes, int n_in,
                              void* d_out, int out_size, void* d_ws, size_t ws_size,
                              hipStream_t stream) {
    const float* x      = (const float*)d_in[0];
    const int*   ei     = (const int*)d_in[1];
    const float* w1_l   = (const float*)d_in[2];
    const float* b1     = (const float*)d_in[3];
    const float* w1_r   = (const float*)d_in[4];
    const float* w2_l   = (const float*)d_in[5];
    const float* b2     = (const float*)d_in[6];
    const float* w2_r   = (const float*)d_in[7];
    const float* w_lin1 = (const float*)d_in[8];
    const float* b_lin1 = (const float*)d_in[9];
    const float* ln_g   = (const float*)d_in[10];
    const float* ln_b   = (const float*)d_in[11];
    const float* w_lin2 = (const float*)d_in[12];
    const float* b_lin2 = (const float*)d_in[13];
    float* out = (float*)d_out;

    char* ws = (char*)d_ws;
    // workspace layout (bytes), liveness-based reuse (max ~161.2MB):
    //   [0,          60,817,408)  Ac1 bf16 [N][256] (gather1->conv1)
    //                             -> wT bf16 [3712][7424] (transpose->lin1)
    //   [60,817,408, 91,226,112)  h1b bf16 [N][128] (conv1->conv2)
    //                             -> t1b fp32 [1024][3712] (lin1->tail; h1b dead)
    //   [91,226,112, 121,634,816) xb bf16 (xconv->gather1) -> q bf16 (conv2->gather2)
    //   [121,634,816,136,839,168) pairs int2[E] (sortC->sortD) -> t1a fp32 (lin1->tail)
    //   [136,839,168,137,314,304) cnt int[N]
    //   [137,314,304,137,789,440) rowend int[N]
    //   [137,789,440,138,220,032) HT int[464*232]
    //   [138,220,032,145,822,208) ssrc int[E]
    //   [145,822,208,161,026,560) h2bf bf16 [N][64] (gather2->lin1)
    //   [161,026,560,161,092,096) BT1 ; +512 bias1p ; +32K BT2
    __hip_bfloat16* Ac1   = (__hip_bfloat16*)(ws + 0);
    __hip_bfloat16* wT    = (__hip_bfloat16*)(ws + 0);
    __hip_bfloat16* h1b   = (__hip_bfloat16*)(ws + 60817408);
    float* t1b            = (float*)(ws + 60817408);
    __hip_bfloat16* xb    = (__hip_bfloat16*)(ws + 91226112);
    __hip_bfloat16* q     = (__hip_bfloat16*)(ws + 91226112);
    int2*  pairs          = (int2*)(ws + 121634816);
    float* t1a            = (float*)(ws + 121634816);
    int*   cnt            = (int*)(ws + 136839168);
    int*   rowend         = (int*)(ws + 137314304);
    int*   HT             = (int*)(ws + 137789440);
    int*   ssrc           = (int*)(ws + 138220032);
    __hip_bfloat16* h2bf  = (__hip_bfloat16*)(ws + 145822208);
    __hip_bfloat16* BT1   = (__hip_bfloat16*)(ws + 161026560);
    float* bias1p         = (float*)(ws + 161092096);
    __hip_bfloat16* BT2   = (__hip_bfloat16*)(ws + 161092608);

    const int* src = ei;
    const int* dst = ei + N_EDGES;

    // --- CSR build: deterministic 2-level counting sort ---
    sortA_kernel<<<NBLK, 256, 0, stream>>>(dst, HT);
    sortB_kernel<<<1, 1024, 0, stream>>>(HT);
    sortC_kernel<<<NBLK, 256, 0, stream>>>(src, dst, HT, pairs);
    sortD_kernel<<<BUCKETS, 256, 0, stream>>>(pairs, HT, ssrc, cnt, rowend);

    // --- padded bf16 weights + bf16 x ---
    concat1_kernel<<<(128 * 256 + 255) / 256, 256, 0, stream>>>(w1_l, w1_r, b1, BT1, bias1p);
    concat2_kernel<<<(128 * 128 + 255) / 256, 256, 0, stream>>>(w2_l, w2_r, BT2);
    xconv_kernel<<<(int)(((long)N_NODES * 58 + 255) / 256), 256, 0, stream>>>(x, xb);

    // --- conv1: gather-mean (quarter-wave) then MFMA GEMM ---
    gather1_kernel<<<(N_NODES + 3) / 4, 256, 0, stream>>>(ssrc, rowend, cnt, xb, Ac1);
    conv_mfma_kernel<<<N_NODES / 128, 256, 0, stream>>>(Ac1, 256, BT1, bias1p, h1b, 1);

    // --- conv2: project first (q = h1 @ [w2_l|w2_r]), gather, combine ---
    conv_mfma_kernel<<<N_NODES / 128, 256, 0, stream>>>(h1b, 128, BT2, nullptr, q, 0);
    gather2_kernel<<<(N_NODES + 3) / 4, 256, 0, stream>>>(ssrc, rowend, cnt, q, b2, h2bf);

    // --- lin1 (bf16 MFMA, 64x128 tiles, split-K x2); wT overlaps dead Ac1,
    //     t1b overlays dead h1b, t1a overlays dead pairs ---
    transpose_bf16_kernel<<<dim3(D1 / 32, KDIM / 32), 256, 0, stream>>>(w_lin1, wT);
    lin1_mfma_kernel<<<1024, 256, 0, stream>>>(h2bf, wT, t1a, t1b);

    // --- (t1a+t1b+bias) + layernorm + mish + lin2 ---
    tail_kernel<<<BATCH, 256, 0, stream>>>(t1a, t1b, b_lin1, ln_g, ln_b, w_lin2, b_lin2, out);
}

// Round 9
// 633.961 us; speedup vs baseline: 4.9531x; 1.0471x over previous
//
#include <hip/hip_runtime.h>
#include <hip/hip_bf16.h>
#include <cstdint>

#define N_NODES 118784
#define N_EDGES 1900544
#define NROI 116
#define HID 64
#define D1 3712
#define BATCH 1024
#define KDIM 7424   // N_ROI * HIDDEN

// sort geometry: 232 blocks x 8192 edges == N_EDGES ; 464 buckets x 256 nodes == N_NODES
#define EPB 8192
#define NBLK 232
#define BUCKETS 464

typedef __attribute__((ext_vector_type(8))) short s16x8;
typedef __attribute__((ext_vector_type(4))) float f32x4;

__device__ __forceinline__ float mishf(float x) {
    if (x > 20.f) return x;
    float e = __expf(x);
    float n = e * e + 2.f * e;
    return x * n / (n + 2.f);
}
__device__ __forceinline__ float bflo(unsigned u) { return __uint_as_float(u << 16); }
__device__ __forceinline__ float bfhi(unsigned u) { return __uint_as_float(u & 0xFFFF0000u); }

// --- fused prep: BT1/bias1p (blocks 0..127), BT2 (128..191), xb (192..) ------
__global__ __launch_bounds__(256) void prep_kernel(
    const float* __restrict__ w1_l, const float* __restrict__ w1_r,
    const float* __restrict__ b1,
    const float* __restrict__ w2_l, const float* __restrict__ w2_r,
    const float* __restrict__ x,
    __hip_bfloat16* __restrict__ BT1, float* __restrict__ bias1p,
    __hip_bfloat16* __restrict__ BT2, __hip_bfloat16* __restrict__ xb) {
    int bid = blockIdx.x, t = threadIdx.x;
    if (bid < 128) {            // BT1 [128][256] = padded [w1_l; w1_r]^T
        int idx = bid * 256 + t;
        int j = idx >> 8, k = idx & 255;
        float v = 0.f;
        if (j < NROI) {
            if (k < NROI) v = w1_l[k * NROI + j];
            else if (k < 2 * NROI) v = w1_r[(k - NROI) * NROI + j];
        }
        BT1[idx] = __float2bfloat16(v);
        if (idx < 128) bias1p[idx] = (idx < NROI) ? b1[idx] : 0.f;
    } else if (bid < 192) {     // BT2 [128][128] = padded [w2_l | w2_r]^T
        int idx = (bid - 128) * 256 + t;
        int j = idx >> 7, k = idx & 127;
        float v = 0.f;
        if (k < NROI) v = (j < HID) ? w2_l[k * HID + j] : w2_r[k * HID + (j - HID)];
        BT2[idx] = __float2bfloat16(v);
    } else {                    // xb: x fp32 -> bf16, 2 elems/thread
        long i = (long)(bid - 192) * 256 + t;     // grid sized so i < N*58 exactly
        float2 v = *(const float2*)(x + 2 * i);
        __hip_bfloat162 o;
        o.x = __float2bfloat16(v.x);
        o.y = __float2bfloat16(v.y);
        *(__hip_bfloat162*)((__hip_bfloat16*)xb + 2 * i) = o;
    }
}

// =============== deterministic CSR build via 2-level counting sort ===========
__global__ __launch_bounds__(256) void sortA_kernel(const int* __restrict__ dst,
                                                    int* __restrict__ HT) {
    __shared__ int h[BUCKETS];
    int t = threadIdx.x;
    for (int i = t; i < BUCKETS; i += 256) h[i] = 0;
    __syncthreads();
    int base = blockIdx.x * EPB;
    for (int i = t; i < EPB; i += 256) atomicAdd(&h[dst[base + i] >> 8], 1);
    __syncthreads();
    for (int i = t; i < BUCKETS; i += 256) HT[i * NBLK + blockIdx.x] = h[i];
}

__global__ __launch_bounds__(1024) void sortB_kernel(int* __restrict__ HT) {
    const int L = BUCKETS * NBLK;   // 107648
    __shared__ int sh[1024];
    __shared__ int carry;
    int t = threadIdx.x;
    if (t == 0) carry = 0;
    __syncthreads();
    for (int base = 0; base < L; base += 4096) {
        int i0 = base + 4 * t;
        int4 v = {0, 0, 0, 0};
        if (i0 + 3 < L) v = *(const int4*)(HT + i0);
        else {
            if (i0 < L) v.x = HT[i0];
            if (i0 + 1 < L) v.y = HT[i0 + 1];
            if (i0 + 2 < L) v.z = HT[i0 + 2];
        }
        int s4 = v.x + v.y + v.z + v.w;
        sh[t] = s4;
        __syncthreads();
        for (int d = 1; d < 1024; d <<= 1) {
            int a = (t >= d) ? sh[t - d] : 0;
            __syncthreads();
            sh[t] += a;
            __syncthreads();
        }
        int excl = sh[t] - s4 + carry;
        int4 o;
        o.x = excl; o.y = excl + v.x; o.z = o.y + v.y; o.w = o.z + v.z;
        if (i0 + 3 < L) *(int4*)(HT + i0) = o;
        else {
            if (i0 < L) HT[i0] = o.x;
            if (i0 + 1 < L) HT[i0 + 1] = o.y;
            if (i0 + 2 < L) HT[i0 + 2] = o.z;
        }
        __syncthreads();
        if (t == 1023) carry += sh[1023];
        __syncthreads();
    }
}

// C: scatter packed (src | dlow<<24) into bucket-sorted order (4B vs 8B pairs)
__global__ __launch_bounds__(256) void sortC_kernel(const int* __restrict__ src,
                                                    const int* __restrict__ dst,
                                                    const int* __restrict__ HT,
                                                    int* __restrict__ pk) {
    __shared__ int cur[BUCKETS];
    int t = threadIdx.x;
    for (int i = t; i < BUCKETS; i += 256) cur[i] = HT[i * NBLK + blockIdx.x];
    __syncthreads();
    int base = blockIdx.x * EPB;
    for (int i = t; i < EPB; i += 256) {
        int d = dst[base + i];
        int s = src[base + i];
        int pos = atomicAdd(&cur[d >> 8], 1);
        pk[pos] = s | ((d & 255) << 24);    // src < 2^17, node-in-bucket in [24:32)
    }
}

__global__ __launch_bounds__(256) void sortD_kernel(const int* __restrict__ pk,
                                                    const int* __restrict__ HT,
                                                    int* __restrict__ ssrc,
                                                    int* __restrict__ cnt,
                                                    int* __restrict__ rowend) {
    __shared__ int h[256], sc_[256], cur[256];
    int b = blockIdx.x;
    int t = threadIdx.x;
    int start = HT[b * NBLK];
    int end = (b == BUCKETS - 1) ? N_EDGES : HT[(b + 1) * NBLK];
    h[t] = 0;
    __syncthreads();
    for (int i = start + t; i < end; i += 256) atomicAdd(&h[((unsigned)pk[i]) >> 24], 1);
    __syncthreads();
    int v = h[t];
    sc_[t] = v;
    __syncthreads();
    for (int d = 1; d < 256; d <<= 1) {
        int a = (t >= d) ? sc_[t - d] : 0;
        __syncthreads();
        sc_[t] += a;
        __syncthreads();
    }
    int excl = sc_[t] - v;
    int node = b * 256 + t;
    cnt[node] = v;
    rowend[node] = start + excl + v;
    cur[t] = start + excl;
    __syncthreads();
    for (int i = start + t; i < end; i += 256) {
        int p = pk[i];
        int pos = atomicAdd(&cur[((unsigned)p) >> 24], 1);
        ssrc[pos] = p & 0xFFFFFF;
    }
}

// --- conv1 gather: 4 neighbors/instr via quarter-wave, 16B loads -------------
// Ac1[n] = [ bf16(mean_{j in N(n)} xb[j]) (116) | xb[n] (116) | 0 (24) ]
__global__ __launch_bounds__(256) void gather1_kernel(
    const int* __restrict__ ssrc, const int* __restrict__ rowend,
    const int* __restrict__ cnt, const __hip_bfloat16* __restrict__ xb,
    __hip_bfloat16* __restrict__ Ac1) {
    int node = blockIdx.x * 4 + (threadIdx.x >> 6);
    int lane = threadIdx.x & 63;
    if (node >= N_NODES) return;
    int deg = cnt[node];
    int start = rowend[node] - deg;
    const int qw = lane >> 4;   // quarter: which of 4 in-flight neighbors
    const int l  = lane & 15;   // 16B chunk (0..14 valid; l=14 half-masked)
    const unsigned short* xbs = (const unsigned short*)xb;
    float f0 = 0.f, f1 = 0.f, f2 = 0.f, f3 = 0.f;
    float f4 = 0.f, f5 = 0.f, f6 = 0.f, f7 = 0.f;

#define G1Q(J)                                                                  \
    {                                                                           \
        int jj = (J) + qw;                                                      \
        int s = __shfl(idx, jj);                                                \
        ulonglong2 u = {0ull, 0ull};                                            \
        if (l < 15 && jj < n)                                                   \
            u = *(const ulonglong2*)(xbs + (long)s * NROI + l * 8);             \
        if (l == 14) u.y = 0ull;                                                \
        unsigned a0 = (unsigned)u.x, a1 = (unsigned)(u.x >> 32);                \
        unsigned a2 = (unsigned)u.y, a3 = (unsigned)(u.y >> 32);                \
        f0 += bflo(a0); f1 += bfhi(a0); f2 += bflo(a1); f3 += bfhi(a1);         \
        f4 += bflo(a2); f5 += bfhi(a2); f6 += bflo(a3); f7 += bfhi(a3);         \
    }

    for (int base = 0; base < deg; base += 64) {
        int n = min(deg - base, 64);
        int idx = (lane < n) ? ssrc[start + base + lane] : 0;
        for (int j = 0; j < n; j += 16) {
            G1Q(j) G1Q(j + 4) G1Q(j + 8) G1Q(j + 12)
        }
    }
#undef G1Q
    f0 += __shfl_xor(f0, 16); f0 += __shfl_xor(f0, 32);
    f1 += __shfl_xor(f1, 16); f1 += __shfl_xor(f1, 32);
    f2 += __shfl_xor(f2, 16); f2 += __shfl_xor(f2, 32);
    f3 += __shfl_xor(f3, 16); f3 += __shfl_xor(f3, 32);
    f4 += __shfl_xor(f4, 16); f4 += __shfl_xor(f4, 32);
    f5 += __shfl_xor(f5, 16); f5 += __shfl_xor(f5, 32);
    f6 += __shfl_xor(f6, 16); f6 += __shfl_xor(f6, 32);
    f7 += __shfl_xor(f7, 16); f7 += __shfl_xor(f7, 32);

    unsigned short* rowp = (unsigned short*)Ac1 + (long)node * 256;
    if (lane < 15) {                 // mean chunks
        float inv = 1.f / fmaxf((float)deg, 1.f);
        __hip_bfloat162 p0, p1, p2, p3;
        p0.x = __float2bfloat16(f0 * inv); p0.y = __float2bfloat16(f1 * inv);
        p1.x = __float2bfloat16(f2 * inv); p1.y = __float2bfloat16(f3 * inv);
        p2.x = __float2bfloat16(f4 * inv); p2.y = __float2bfloat16(f5 * inv);
        p3.x = __float2bfloat16(f6 * inv); p3.y = __float2bfloat16(f7 * inv);
        unsigned u0 = *(unsigned*)&p0, u1 = *(unsigned*)&p1;
        unsigned u2 = *(unsigned*)&p2, u3 = *(unsigned*)&p3;
        unsigned long long w0 = (unsigned long long)u0 | ((unsigned long long)u1 << 32);
        unsigned long long w1 = (unsigned long long)u2 | ((unsigned long long)u3 << 32);
        if (lane < 14) {
            ulonglong2 o = {w0, w1};
            *(ulonglong2*)(rowp + lane * 8) = o;
        } else {
            *(unsigned long long*)(rowp + 112) = w0;   // feats 112..115
        }
    } else if (lane >= 16 && lane < 45) {   // self-row copy, 29 x 8B
        int sl = lane - 16;
        *(unsigned long long*)(rowp + NROI + 4 * sl) =
            *(const unsigned long long*)(xbs + (long)node * NROI + 4 * sl);
    } else if (lane >= 45 && lane < 51) {   // zero pad, 6 x 8B
        int zl = lane - 45;
        *(unsigned long long*)(rowp + 2 * NROI + 4 * zl) = 0ull;
    }
}

// --- conv2 gather: 4 neighbors/instr via quarter-wave, 8B loads --------------
__global__ __launch_bounds__(256) void gather2_kernel(
    const int* __restrict__ ssrc, const int* __restrict__ rowend,
    const int* __restrict__ cnt, const __hip_bfloat16* __restrict__ q,
    const float* __restrict__ b2, __hip_bfloat16* __restrict__ h2bf) {
    int node = blockIdx.x * 4 + (threadIdx.x >> 6);
    int lane = threadIdx.x & 63;
    if (node >= N_NODES) return;
    int deg = cnt[node];
    int start = rowend[node] - deg;
    const int qw = lane >> 4;
    const int l  = lane & 15;      // features 4l..4l+3
    const unsigned short* qs = (const unsigned short*)q;
    float g0 = 0.f, g1 = 0.f, g2 = 0.f, g3 = 0.f;

#define G2Q(J)                                                                  \
    {                                                                           \
        int jj = (J) + qw;                                                      \
        int s = __shfl(idx, jj);                                                \
        unsigned long long u = 0ull;                                            \
        if (jj < n) u = *(const unsigned long long*)(qs + (long)s * 128 + l * 4); \
        unsigned a0 = (unsigned)u, a1 = (unsigned)(u >> 32);                    \
        g0 += bflo(a0); g1 += bfhi(a0); g2 += bflo(a1); g3 += bfhi(a1);         \
    }

    for (int base = 0; base < deg; base += 64) {
        int n = min(deg - base, 64);
        int idx = (lane < n) ? ssrc[start + base + lane] : 0;
        for (int j = 0; j < n; j += 16) {
            G2Q(j) G2Q(j + 4) G2Q(j + 8) G2Q(j + 12)
        }
    }
#undef G2Q
    g0 += __shfl_xor(g0, 16); g0 += __shfl_xor(g0, 32);
    g1 += __shfl_xor(g1, 16); g1 += __shfl_xor(g1, 32);
    g2 += __shfl_xor(g2, 16); g2 += __shfl_xor(g2, 32);
    g3 += __shfl_xor(g3, 16); g3 += __shfl_xor(g3, 32);

    if (lane < 16) {
        float c = fmaxf((float)deg, 1.f);
        unsigned long long su = *(const unsigned long long*)(qs + (long)node * 128 + 64 + l * 4);
        unsigned s0 = (unsigned)su, s1 = (unsigned)(su >> 32);
        float4 bb = *(const float4*)(b2 + 4 * l);
        __hip_bfloat162 o0, o1;
        o0.x = __float2bfloat16(mishf(g0 / c + bflo(s0) + bb.x));
        o0.y = __float2bfloat16(mishf(g1 / c + bfhi(s0) + bb.y));
        o1.x = __float2bfloat16(mishf(g2 / c + bflo(s1) + bb.z));
        o1.y = __float2bfloat16(mishf(g3 / c + bfhi(s1) + bb.w));
        unsigned u0 = *(unsigned*)&o0, u1 = *(unsigned*)&o1;
        *(unsigned long long*)((unsigned short*)h2bf + (long)node * 64 + 4 * l) =
            (unsigned long long)u0 | ((unsigned long long)u1 << 32);
    }
}

// --- fused conv1+conv2 projection: q = (mish(Ac1 @ BT1^T + b1)) @ BT2^T ------
// h1 tile [128][128] round-trips through LDS (C-layout -> A-layout), never HBM.
__global__ __launch_bounds__(256) void conv_fused_kernel(
    const __hip_bfloat16* __restrict__ Ac1,   // [N][256]
    const __hip_bfloat16* __restrict__ BT1,   // [128][256]
    const float* __restrict__ bias1p,         // [128]
    const __hip_bfloat16* __restrict__ BT2,   // [128][128]
    __hip_bfloat16* __restrict__ q) {         // [N][128]
    __shared__ short As[128][40];
    __shared__ short Bs[128][40];
    __shared__ short Ah[128][136];   // stride 136 shorts = 272B: 16B-aligned, 2-way banks
    const int t = threadIdx.x;
    const long row0 = (long)blockIdx.x * 128;

    const int sr = t >> 2;
    const int sc = (t & 3) << 3;
    const short* Ap = (const short*)Ac1 + (row0 + sr) * 256 + sc;
    const short* Bp = (const short*)BT1 + sr * 256 + sc;

    s16x8 ra0 = *(const s16x8*)(Ap);
    s16x8 ra1 = *(const s16x8*)(Ap + 64 * 256);
    s16x8 rb0 = *(const s16x8*)(Bp);
    s16x8 rb1 = *(const s16x8*)(Bp + 64 * 256);

    const int lane = t & 63;
    const int wid = t >> 6;
    const int wr = (wid >> 1) << 6;
    const int wc = (wid & 1) << 6;
    const int fm = lane & 15;
    const int fk = (lane >> 4) << 3;
    const int quad4 = (lane >> 4) << 2;

    f32x4 acc[4][4];
#pragma unroll
    for (int i = 0; i < 4; i++)
#pragma unroll
        for (int j = 0; j < 4; j++) acc[i][j] = (f32x4){0.f, 0.f, 0.f, 0.f};

    // phase 1: K=256 over BT1
    for (int k0 = 0; k0 < 256; k0 += 32) {
        *(s16x8*)&As[sr][sc] = ra0;
        *(s16x8*)&As[sr + 64][sc] = ra1;
        *(s16x8*)&Bs[sr][sc] = rb0;
        *(s16x8*)&Bs[sr + 64][sc] = rb1;
        __syncthreads();
        if (k0 + 32 < 256) {
            ra0 = *(const s16x8*)(Ap + k0 + 32);
            ra1 = *(const s16x8*)(Ap + 64 * 256 + k0 + 32);
            rb0 = *(const s16x8*)(Bp + k0 + 32);
            rb1 = *(const s16x8*)(Bp + 64 * 256 + k0 + 32);
        }
        s16x8 a[4], b[4];
#pragma unroll
        for (int i = 0; i < 4; i++) a[i] = *(const s16x8*)&As[wr + i * 16 + fm][fk];
#pragma unroll
        for (int j = 0; j < 4; j++) b[j] = *(const s16x8*)&Bs[wc + j * 16 + fm][fk];
#pragma unroll
        for (int i = 0; i < 4; i++)
#pragma unroll
            for (int j = 0; j < 4; j++)
                acc[i][j] = __builtin_amdgcn_mfma_f32_16x16x32_bf16(
                    a[i], b[j], acc[i][j], 0, 0, 0);
        __syncthreads();
    }

    // mish(h1 + bias) -> Ah (LDS, A-operand layout source)
    __hip_bfloat16* Ahb = (__hip_bfloat16*)&Ah[0][0];
#pragma unroll
    for (int i = 0; i < 4; i++) {
#pragma unroll
        for (int j = 0; j < 4; j++) {
            int gc = wc + j * 16 + fm;
            float bv = bias1p[gc];
#pragma unroll
            for (int r = 0; r < 4; r++) {
                int lr = wr + i * 16 + quad4 + r;
                Ahb[lr * 136 + gc] = __float2bfloat16(mishf(acc[i][j][r] + bv));
            }
        }
    }
    __syncthreads();

    // phase 2: q = h1 @ BT2^T, K=128, BT2 staged via Bs (L2-hot)
    f32x4 acc2[4][4];
#pragma unroll
    for (int i = 0; i < 4; i++)
#pragma unroll
        for (int j = 0; j < 4; j++) acc2[i][j] = (f32x4){0.f, 0.f, 0.f, 0.f};

    const short* Bp2 = (const short*)BT2 + sr * 128 + sc;
    for (int k0 = 0; k0 < 128; k0 += 32) {
        s16x8 c0 = *(const s16x8*)(Bp2 + k0);
        s16x8 c1 = *(const s16x8*)(Bp2 + 64 * 128 + k0);
        *(s16x8*)&Bs[sr][sc] = c0;
        *(s16x8*)&Bs[sr + 64][sc] = c1;
        __syncthreads();
        s16x8 a[4], b[4];
#pragma unroll
        for (int i = 0; i < 4; i++) a[i] = *(const s16x8*)&Ah[wr + i * 16 + fm][k0 + fk];
#pragma unroll
        for (int j = 0; j < 4; j++) b[j] = *(const s16x8*)&Bs[wc + j * 16 + fm][fk];
#pragma unroll
        for (int i = 0; i < 4; i++)
#pragma unroll
            for (int j = 0; j < 4; j++)
                acc2[i][j] = __builtin_amdgcn_mfma_f32_16x16x32_bf16(
                    a[i], b[j], acc2[i][j], 0, 0, 0);
        __syncthreads();
    }

#pragma unroll
    for (int i = 0; i < 4; i++) {
#pragma unroll
        for (int j = 0; j < 4; j++) {
            int gc = wc + j * 16 + fm;
#pragma unroll
            for (int r = 0; r < 4; r++) {
                long gr = row0 + wr + i * 16 + quad4 + r;
                q[gr * 128 + gc] = __float2bfloat16(acc2[i][j][r]);
            }
        }
    }
}

// --- tiled transpose + fp32->bf16: W[7424][3712] -> WT[3712][7424] -----------
__global__ __launch_bounds__(256) void transpose_bf16_kernel(
    const float* __restrict__ W, __hip_bfloat16* __restrict__ WT) {
    __shared__ float tile[32][33];
    const int t = threadIdx.x;
    const int tn = t & 31, tk = t >> 5;
    const int n0 = blockIdx.x * 32;
    const int k0 = blockIdx.y * 32;
#pragma unroll
    for (int i = 0; i < 4; i++) {
        tile[tk + i * 8][tn] = W[(long)(k0 + tk + i * 8) * D1 + (n0 + tn)];
    }
    __syncthreads();
#pragma unroll
    for (int i = 0; i < 4; i++) {
        int n = n0 + tk + i * 8;
        int k = k0 + tn;
        WT[(long)n * KDIM + k] = __float2bfloat16(tile[tn][tk + i * 8]);
    }
}

// --- lin1: 128x128 tiles (m97 structure), split-K x4, XCD col-grouped --------
// Grid 1024: xx=id&7; g=id>>3: r=g&7 (8 row tiles), ks=(g>>3)&3, cg=g>>5;
// col=xx+8*cg (29 valid). Partials -> T[ks][1024][3712].
__global__ __launch_bounds__(256) void lin1_mfma_kernel(
    const __hip_bfloat16* __restrict__ Abf,
    const __hip_bfloat16* __restrict__ BTbf,
    float* __restrict__ T) {
    __shared__ short As[128][40];
    __shared__ short Bs[128][40];
    const int t = threadIdx.x;
    const int id = blockIdx.x;
    const int xx = id & 7;
    const int g = id >> 3;
    const int r = g & 7;
    const int ks = (g >> 3) & 3;
    const int c = xx + 8 * (g >> 5);
    if (c >= D1 / 128) return;     // 29 col stripes
    const long row0 = (long)r * 128;
    const long col0 = (long)c * 128;
    const int kbase = ks * (KDIM / 4);       // 1856-chunk
    float* __restrict__ Cp = T + (long)ks * BATCH * D1;

    const int sr = t >> 2;
    const int sc = (t & 3) << 3;
    const short* Ap = (const short*)Abf + (row0 + sr) * KDIM + kbase + sc;
    const short* Bp = (const short*)BTbf + (col0 + sr) * KDIM + kbase + sc;

    s16x8 ra0 = *(const s16x8*)(Ap);
    s16x8 ra1 = *(const s16x8*)(Ap + 64 * KDIM);
    s16x8 rb0 = *(const s16x8*)(Bp);
    s16x8 rb1 = *(const s16x8*)(Bp + 64 * KDIM);

    const int lane = t & 63;
    const int wid = t >> 6;
    const int wr = (wid >> 1) << 6;
    const int wc = (wid & 1) << 6;
    const int fm = lane & 15;
    const int fk = (lane >> 4) << 3;

    f32x4 acc[4][4];
#pragma unroll
    for (int i = 0; i < 4; i++)
#pragma unroll
        for (int j = 0; j < 4; j++) acc[i][j] = (f32x4){0.f, 0.f, 0.f, 0.f};

    for (int k0 = 0; k0 < KDIM / 4; k0 += 32) {
        *(s16x8*)&As[sr][sc] = ra0;
        *(s16x8*)&As[sr + 64][sc] = ra1;
        *(s16x8*)&Bs[sr][sc] = rb0;
        *(s16x8*)&Bs[sr + 64][sc] = rb1;
        __syncthreads();
        if (k0 + 32 < KDIM / 4) {
            ra0 = *(const s16x8*)(Ap + k0 + 32);
            ra1 = *(const s16x8*)(Ap + 64 * KDIM + k0 + 32);
            rb0 = *(const s16x8*)(Bp + k0 + 32);
            rb1 = *(const s16x8*)(Bp + 64 * KDIM + k0 + 32);
        }
        s16x8 a[4], b[4];
#pragma unroll
        for (int i = 0; i < 4; i++) a[i] = *(const s16x8*)&As[wr + i * 16 + fm][fk];
#pragma unroll
        for (int j = 0; j < 4; j++) b[j] = *(const s16x8*)&Bs[wc + j * 16 + fm][fk];
#pragma unroll
        for (int i = 0; i < 4; i++)
#pragma unroll
            for (int j = 0; j < 4; j++)
                acc[i][j] = __builtin_amdgcn_mfma_f32_16x16x32_bf16(
                    a[i], b[j], acc[i][j], 0, 0, 0);
        __syncthreads();
    }

#pragma unroll
    for (int i = 0; i < 4; i++) {
#pragma unroll
        for (int j = 0; j < 4; j++) {
            int gc = (int)col0 + wc + j * 16 + fm;
#pragma unroll
            for (int r2 = 0; r2 < 4; r2++) {
                long gr = row0 + wr + i * 16 + ((lane >> 4) << 2) + r2;
                Cp[gr * D1 + gc] = acc[i][j][r2];
            }
        }
    }
}

// --- fused (sum 4 partials + bias) + layernorm + mish + lin2 tail ------------
// Values cached in registers: single read of the partials.
__global__ __launch_bounds__(256) void tail_kernel(
    const float* __restrict__ T, const float* __restrict__ bias,
    const float* __restrict__ g, const float* __restrict__ b,
    const float* __restrict__ w2, const float* __restrict__ b2,
    float* __restrict__ out) {
    int row = blockIdx.x;
    const float* p0 = T + (long)row * D1;
    const float* p1 = p0 + (long)BATCH * D1;
    const float* p2 = p1 + (long)BATCH * D1;
    const float* p3 = p2 + (long)BATCH * D1;
    int t = threadIdx.x;
    int w = t >> 6, lane = t & 63;
    float vc[15];
    float s = 0.f, ss = 0.f;
    int m = 0;
    for (int i = t; i < D1; i += 256) {
        float v = (p0[i] + p1[i]) + (p2[i] + p3[i]) + bias[i];
        vc[m++] = v;
        s += v;
        ss += v * v;
    }
    for (int d = 32; d > 0; d >>= 1) {
        s += __shfl_down(s, d);
        ss += __shfl_down(ss, d);
    }
    __shared__ float sh[8];
    if (lane == 0) { sh[w] = s; sh[4 + w] = ss; }
    __syncthreads();
    if (t == 0) {
        sh[0] = sh[0] + sh[1] + sh[2] + sh[3];
        sh[4] = sh[4] + sh[5] + sh[6] + sh[7];
    }
    __syncthreads();
    float mu = sh[0] * (1.f / D1);
    float var = sh[4] * (1.f / D1) - mu * mu;
    float rs = rsqrtf(var + 1e-5f);
    float d0 = 0.f, d1 = 0.f;
    m = 0;
    for (int i = t; i < D1; i += 256) {
        float v = (vc[m++] - mu) * rs * g[i] + b[i];
        v = mishf(v);
        d0 += v * w2[2 * i];
        d1 += v * w2[2 * i + 1];
    }
    for (int d = 32; d > 0; d >>= 1) {
        d0 += __shfl_down(d0, d);
        d1 += __shfl_down(d1, d);
    }
    __shared__ float sh2[8];
    if (lane == 0) { sh2[w] = d0; sh2[4 + w] = d1; }
    __syncthreads();
    if (t == 0) {
        out[2 * row] = sh2[0] + sh2[1] + sh2[2] + sh2[3] + b2[0];
        out[2 * row + 1] = sh2[4] + sh2[5] + sh2[6] + sh2[7] + b2[1];
    }
}

extern "C" void kernel_launch(void* const* d_in, const int* in_sizes, int n_in,
                              void* d_out, int out_size, void* d_ws, size_t ws_size,
                              hipStream_t stream) {
    const float* x      = (const float*)d_in[0];
    const int*   ei     = (const int*)d_in[1];
    const float* w1_l   = (const float*)d_in[2];
    const float* b1     = (const float*)d_in[3];
    const float* w1_r   = (const float*)d_in[4];
    const float* w2_l   = (const float*)d_in[5];
    const float* b2     = (const float*)d_in[6];
    const float* w2_r   = (const float*)d_in[7];
    const float* w_lin1 = (const float*)d_in[8];
    const float* b_lin1 = (const float*)d_in[9];
    const float* ln_g   = (const float*)d_in[10];
    const float* ln_b   = (const float*)d_in[11];
    const float* w_lin2 = (const float*)d_in[12];
    const float* b_lin2 = (const float*)d_in[13];
    float* out = (float*)d_out;

    char* ws = (char*)d_ws;
    // workspace layout (bytes), liveness-based reuse (max ~161.1MB):
    //   [0,          60,817,408)  Ac1 bf16 [N][256] (gather1->conv_fused)
    //                             -> wT bf16 [3712][7424] (transpose->lin1)
    //   [60,817,408, 121,634,816) T fp32 [4][1024][3712] partials (lin1->tail)
    //     overlays: xb/q bf16 at 91,226,112 (prep->gather1 / conv_fused->gather2,
    //     both dead before lin1 writes T)
    //   [121,634,816,129,236,992) pk int[E] packed pairs (sortC->sortD)
    //   [136,839,168,137,314,304) cnt int[N]
    //   [137,314,304,137,789,440) rowend int[N]
    //   [137,789,440,138,220,032) HT int[464*232]
    //   [138,220,032,145,822,208) ssrc int[E]
    //   [145,822,208,161,026,560) h2bf bf16 [N][64] (gather2->lin1)
    //   [161,026,560,...)         BT1 ; bias1p ; BT2
    __hip_bfloat16* Ac1   = (__hip_bfloat16*)(ws + 0);
    __hip_bfloat16* wT    = (__hip_bfloat16*)(ws + 0);
    float* T              = (float*)(ws + 60817408);
    __hip_bfloat16* xb    = (__hip_bfloat16*)(ws + 91226112);
    __hip_bfloat16* q     = (__hip_bfloat16*)(ws + 91226112);
    int*   pk             = (int*)(ws + 121634816);
    int*   cnt            = (int*)(ws + 136839168);
    int*   rowend         = (int*)(ws + 137314304);
    int*   HT             = (int*)(ws + 137789440);
    int*   ssrc           = (int*)(ws + 138220032);
    __hip_bfloat16* h2bf  = (__hip_bfloat16*)(ws + 145822208);
    __hip_bfloat16* BT1   = (__hip_bfloat16*)(ws + 161026560);
    float* bias1p         = (float*)(ws + 161092096);
    __hip_bfloat16* BT2   = (__hip_bfloat16*)(ws + 161092608);

    const int* src = ei;
    const int* dst = ei + N_EDGES;

    // --- fused prep (BT1 + BT2 + xb) ---
    prep_kernel<<<192 + (int)((long)N_NODES * 58 / 256), 256, 0, stream>>>(
        w1_l, w1_r, b1, w2_l, w2_r, x, BT1, bias1p, BT2, xb);

    // --- CSR build: deterministic 2-level counting sort (packed 4B pairs) ---
    sortA_kernel<<<NBLK, 256, 0, stream>>>(dst, HT);
    sortB_kernel<<<1, 1024, 0, stream>>>(HT);
    sortC_kernel<<<NBLK, 256, 0, stream>>>(src, dst, HT, pk);
    sortD_kernel<<<BUCKETS, 256, 0, stream>>>(pk, HT, ssrc, cnt, rowend);

    // --- conv1 gather-mean, then fused conv1-GEMM + conv2-projection ---
    gather1_kernel<<<(N_NODES + 3) / 4, 256, 0, stream>>>(ssrc, rowend, cnt, xb, Ac1);
    conv_fused_kernel<<<N_NODES / 128, 256, 0, stream>>>(Ac1, BT1, bias1p, BT2, q);

    // --- conv2 aggregation ---
    gather2_kernel<<<(N_NODES + 3) / 4, 256, 0, stream>>>(ssrc, rowend, cnt, q, b2, h2bf);

    // --- lin1 (128x128 m97 structure, split-K x4); wT overlays dead Ac1,
    //     T overlays dead q/xb region ---
    transpose_bf16_kernel<<<dim3(D1 / 32, KDIM / 32), 256, 0, stream>>>(w_lin1, wT);
    lin1_mfma_kernel<<<1024, 256, 0, stream>>>(h2bf, wT, T);

    // --- (sum partials + bias) + layernorm + mish + lin2 ---
    tail_kernel<<<BATCH, 256, 0, stream>>>(T, b_lin1, ln_g, ln_b, w_lin2, b_lin2, out);
}